// Round 9
// baseline (4806834.766 us; speedup 1.0000x reference)
//
#include <hip/hip_runtime.h>

// ---------- types / helpers ----------
typedef short short8 __attribute__((ext_vector_type(8)));
typedef float f32x4 __attribute__((ext_vector_type(4)));

__device__ __forceinline__ float bf2f(unsigned short s) {
    unsigned int u = ((unsigned int)s) << 16;
    return __builtin_bit_cast(float, u);
}
__device__ __forceinline__ unsigned short f2bf(float f) {
    unsigned int u = __builtin_bit_cast(unsigned int, f);
    u += 0x7fffu + ((u >> 16) & 1u);
    return (unsigned short)(u >> 16);
}
__device__ __forceinline__ float sigm(float x) { return 1.0f / (1.0f + __expf(-x)); }

__device__ __forceinline__ void gload16(const void* g, void* l) {
    __builtin_amdgcn_global_load_lds((const __attribute__((address_space(1))) void*)g,
                                     (__attribute__((address_space(3))) void*)l, 16, 0, 0);
}

// L1-bypass 4B load (reads own XCD L2; for XCD-local flag polling)
__device__ __forceinline__ unsigned ld_sc0(const unsigned* p) {
    unsigned v;
    asm volatile("global_load_dword %0, %1, off sc0\n\ts_waitcnt vmcnt(0)"
                 : "=v"(v) : "v"(p) : "memory");
    return v;
}

#define WDOG_POLL 2000000ull   // 20 ms (s_memrealtime ~100 MHz)
#define WDOG_DEC  2000000ull   // 20 ms
#define DEC_WAIT  10000ull     // 100 us decider patience

// ---------- kernel: fp32 -> bf16 vectorized convert ----------
__global__ void conv_bf16(const float4* __restrict__ src, ushort4* __restrict__ dst, int n4) {
    for (int i = blockIdx.x * blockDim.x + threadIdx.x; i < n4; i += gridDim.x * blockDim.x) {
        float4 v = src[i];
        ushort4 o;
        o.x = f2bf(v.x); o.y = f2bf(v.y); o.z = f2bf(v.z); o.w = f2bf(v.w);
        dst[i] = o;
    }
}

// ---------- kernel: transpose+convert 9 weight matrices to bf16 [N][K] ----------
struct PackArgs { const float* src[9]; };

__global__ __launch_bounds__(256) void pack_w(PackArgs pa,
                                              unsigned short* __restrict__ Wx,
                                              unsigned short* __restrict__ Wh,
                                              unsigned short* __restrict__ Wyt) {
    __shared__ float tile[32][33];
    const int z = blockIdx.z;
    const float* S = pa.src[z];
    unsigned short* D = (z < 4) ? Wx + (long)z * 1048576
                                : (z < 8) ? Wh + (long)(z - 4) * 1048576
                                          : Wyt;
    const int tx = threadIdx.x & 31, ty = threadIdx.x >> 5;
    const int rb = blockIdx.y * 32, cb = blockIdx.x * 32;
#pragma unroll
    for (int rr = 0; rr < 4; ++rr) {
        int r = ty + rr * 8;
        tile[r][tx] = S[(long)(rb + r) * 1024 + cb + tx];
    }
    __syncthreads();
#pragma unroll
    for (int rr = 0; rr < 4; ++rr) {
        int r = ty + rr * 8;
        D[(long)(cb + r) * 1024 + rb + tx] = f2bf(tile[tx][r]);
    }
}

// ---------- kernel: small init (bias concat, h0->bf16, flags=0) ----------
__global__ void init_small(const float* __restrict__ h0,
                           const float* __restrict__ bf_, const float* __restrict__ bi_,
                           const float* __restrict__ bc_, const float* __restrict__ bo_,
                           unsigned short* __restrict__ hbuf0,
                           float* __restrict__ bcat, unsigned int* __restrict__ flags) {
    int i = blockIdx.x * blockDim.x + threadIdx.x;
    if (i < 1024) flags[i] = 0u;   // step flags[0..256) | xcc[256..512) | arrive[512] | dec[513]
    if (i < 65536) hbuf0[i] = f2bf(h0[i]);
    if (i < 4096) {
        const float* bs = (i < 1024) ? bf_ : (i < 2048) ? bi_ : (i < 3072) ? bc_ : bo_;
        bcat[i] = bs[i & 1023];
    }
}

// ---------- kernel: 128x128 bf16 MFMA GEMM, A[M][K] x B^T[N][K] + bias ----------
template <int OUT_BF16>
__global__ __launch_bounds__(256) void gemm_bt(const unsigned short* __restrict__ A,
                                               const unsigned short* __restrict__ B,
                                               const float* __restrict__ bias,
                                               void* __restrict__ Cout,
                                               int M, int N, int K) {
    __shared__ unsigned short As[128 * 32];
    __shared__ unsigned short Bs[128 * 32];
    const int l = threadIdx.x;
    const int w = l >> 6, u = l & 63;
    const int wr = w >> 1, wc = w & 1;
    const long rowbase = (long)blockIdx.y * 128;
    const long colbase = (long)blockIdx.x * 128;

    f32x4 acc[4][4] = {};

    const int srow = l >> 2;
    const int sunit = l & 3;

    for (int k0 = 0; k0 < K; k0 += 32) {
#pragma unroll
        for (int i = 0; i < 2; ++i) {
            int row = i * 64 + srow;
            int su = sunit ^ (row & 3);
            gload16(&A[(rowbase + row) * K + k0 + su * 8], &As[i * 2048 + l * 8]);
            gload16(&B[(colbase + row) * K + k0 + su * 8], &Bs[i * 2048 + l * 8]);
        }
        __syncthreads();
        short8 a[4], b[4];
#pragma unroll
        for (int mi = 0; mi < 4; ++mi) {
            int row = wr * 64 + mi * 16 + (u & 15);
            a[mi] = *(const short8*)&As[row * 32 + (((u >> 4) ^ (row & 3))) * 8];
        }
#pragma unroll
        for (int ni = 0; ni < 4; ++ni) {
            int row = wc * 64 + ni * 16 + (u & 15);
            b[ni] = *(const short8*)&Bs[row * 32 + (((u >> 4) ^ (row & 3))) * 8];
        }
#pragma unroll
        for (int mi = 0; mi < 4; ++mi)
#pragma unroll
            for (int ni = 0; ni < 4; ++ni)
                acc[mi][ni] = __builtin_amdgcn_mfma_f32_16x16x32_bf16(a[mi], b[ni], acc[mi][ni], 0, 0, 0);
        __syncthreads();
    }

#pragma unroll
    for (int mi = 0; mi < 4; ++mi) {
#pragma unroll
        for (int ni = 0; ni < 4; ++ni) {
#pragma unroll
            for (int r = 0; r < 4; ++r) {
                long row = rowbase + wr * 64 + mi * 16 + (u >> 4) * 4 + r;
                long col = colbase + wc * 64 + ni * 16 + (u & 15);
                float v = acc[mi][ni][r] + bias[col];
                if (OUT_BF16)
                    ((unsigned short*)Cout)[row * N + col] = f2bf(v);
                else
                    ((float*)Cout)[row * N + col] = v;
            }
        }
    }
}

// ================= GO world: batch-partitioned XCD-local scan (256 WGs) =================
// Group g = {bid: bid%8==g} (32 WGs) owns batch rows [8g,8g+8). WG i=bid>>3 owns hidden
// cols [32i,32i+32) (=128 gate cols). Wave w = K-slice [256w,..+256). Weights in VGPRs.
template <int FAST>
__device__ __forceinline__ void scan_go(
    int g, int i, int l, int w, int u,
    const unsigned short* __restrict__ Whc, const unsigned short* __restrict__ Xg,
    const unsigned short* __restrict__ h0bf, unsigned short* __restrict__ H,
    const float* __restrict__ c0, float* __restrict__ out_h, float* __restrict__ out_c,
    unsigned int* __restrict__ flags, f32x4 (*red)[8][64]) {

    const int rho = l >> 5, chi = l & 31;
    const int arow = u & 15;
    const int kofs = (u >> 4) * 8;

    short8 b[8][8];
#pragma unroll
    for (int n = 0; n < 8; ++n)
#pragma unroll
        for (int kt = 0; kt < 8; ++kt)
            b[n][kt] = *(const short8*)&Whc[(size_t)((n >> 1) * 1024 + 32 * i + 16 * (n & 1) + arow) * 1024
                                            + w * 256 + kt * 32 + kofs];

    float c = c0[(size_t)(8 * g + rho) * 1024 + 32 * i + chi];

    unsigned short xg[4];
#pragma unroll
    for (int ga = 0; ga < 4; ++ga)
        xg[ga] = Xg[(size_t)(8 * g + rho) * 4096 + ga * 1024 + 32 * i + chi];

    const short8 az = {};

#pragma unroll 1
    for (int t = 0; t < 256; ++t) {
        const unsigned short* hp = t ? (H + (size_t)(t - 1) * 65536 + 8 * g * 1024)
                                     : (h0bf + 8 * g * 1024);
        const unsigned short* ab = hp + (size_t)arow * 1024 + w * 256 + kofs;

        f32x4 acc[8] = {};
#pragma unroll
        for (int kt = 0; kt < 8; ++kt) {
            short8 a = (arow < 8) ? *(const short8*)(ab + kt * 32) : az;
#pragma unroll
            for (int n = 0; n < 8; ++n)
                acc[n] = __builtin_amdgcn_mfma_f32_16x16x32_bf16(a, b[n][kt], acc[n], 0, 0, 0);
        }

#pragma unroll
        for (int n = 0; n < 8; ++n)
            red[w][n][u] = acc[n];
        __syncthreads();

        float pre[4];
#pragma unroll
        for (int ga = 0; ga < 4; ++ga) {
            int n = ga * 2 + (chi >> 4);
            int sl = ((rho >> 2) << 4) + (chi & 15);
            int rg = rho & 3;
            const float* r0 = (const float*)&red[0][n][sl];
            const float* r1 = (const float*)&red[1][n][sl];
            const float* r2 = (const float*)&red[2][n][sl];
            const float* r3 = (const float*)&red[3][n][sl];
            pre[ga] = r0[rg] + r1[rg] + r2[rg] + r3[rg] + bf2f(xg[ga]);
        }
        float F = sigm(pre[0]);
        float I = sigm(pre[1]);
        float Cd = tanhf(pre[2]);
        float O = sigm(pre[3]);
        float cn = F * c + I * Cd;
        c = cn;
        float hf = tanhf(cn) * O;

        const size_t hidx = (size_t)(t * 64 + 8 * g + rho) * 1024 + 32 * i + chi;
        if (FAST) {
            H[hidx] = f2bf(hf);  // plain store -> own XCD L2 (consumers same XCD)
        } else {
            __hip_atomic_store(&H[hidx], f2bf(hf), __ATOMIC_RELAXED, __HIP_MEMORY_SCOPE_AGENT);
        }
        if (t == 255) {
            out_h[(size_t)(8 * g + rho) * 1024 + 32 * i + chi] = hf;
            out_c[(size_t)(8 * g + rho) * 1024 + 32 * i + chi] = cn;
        }

        if (t < 255) {
            asm volatile("s_waitcnt vmcnt(0)" ::: "memory");
            __syncthreads();
            if (l == 0) {
                if (FAST)
                    *(volatile unsigned*)&flags[g * 32 + i] = (unsigned)(t + 1);
                else
                    __hip_atomic_store(&flags[g * 32 + i], (unsigned)(t + 1),
                                       __ATOMIC_RELAXED, __HIP_MEMORY_SCOPE_AGENT);
            }
#pragma unroll
            for (int ga = 0; ga < 4; ++ga)
                xg[ga] = Xg[(size_t)((t + 1) * 64 + 8 * g + rho) * 4096 + ga * 1024 + 32 * i + chi];
            const unsigned tgt = (unsigned)(t + 1);
            unsigned long long wd0 = __builtin_amdgcn_s_memrealtime();
            while (true) {
                unsigned f;
                if (FAST)
                    f = (u < 8) ? ld_sc0(&flags[g * 32 + 8 * w + u]) : tgt;
                else
                    f = (u < 8) ? __hip_atomic_load(&flags[g * 32 + 8 * w + u],
                                                    __ATOMIC_RELAXED, __HIP_MEMORY_SCOPE_AGENT)
                                : tgt;
                if (__all(f >= tgt)) break;
                if (__builtin_amdgcn_s_memrealtime() - wd0 > WDOG_POLL) break;  // bug -> absmax
                __builtin_amdgcn_s_sleep(1);
            }
            asm volatile("" ::: "memory");
            __builtin_amdgcn_sched_barrier(0);
        }
    }
}

// ================= NOGO world: proven R5 64-WG scan (bids 0..63) =================
__device__ __forceinline__ void scan64(
    int bid, int l, int w, int u,
    const unsigned short* __restrict__ Whc, const unsigned short* __restrict__ Xg,
    const unsigned short* __restrict__ h0bf, unsigned short* __restrict__ H,
    const float* __restrict__ c0, float* __restrict__ out_h, float* __restrict__ out_c,
    unsigned int* __restrict__ flags, f32x4 (*red)[4][4][64], unsigned short* hs) {

    const int j0 = bid * 16;
    const int jj = u & 15, q = u >> 4;

    short8 b[4][8];
#pragma unroll
    for (int g = 0; g < 4; ++g)
#pragma unroll
        for (int kt = 0; kt < 8; ++kt)
            b[g][kt] = *(const short8*)&Whc[(size_t)(g * 1024 + j0 + jj) * 1024 + w * 256 + kt * 32 + q * 8];

    float c[4];
#pragma unroll
    for (int r = 0; r < 4; ++r)
        c[r] = c0[(size_t)(w * 16 + q * 4 + r) * 1024 + j0 + jj];

    unsigned short xg[4][4];
#pragma unroll
    for (int g = 0; g < 4; ++g)
#pragma unroll
        for (int r = 0; r < 4; ++r)
            xg[g][r] = Xg[(size_t)(w * 16 + q * 4 + r) * 4096 + g * 1024 + j0 + jj];

    const int srow_ = l >> 2, sqtr = l & 3;

#pragma unroll 1
    for (int t = 0; t < 256; ++t) {
        const unsigned short* hp = t ? (H + (size_t)(t - 1) * 65536) : h0bf;

        f32x4 acc[4][4] = {};
#pragma unroll
        for (int kt = 0; kt < 8; ++kt) {
            short8 a[4];
#pragma unroll
            for (int m = 0; m < 4; ++m)
                a[m] = *(const short8*)&hp[(size_t)(m * 16 + jj) * 1024 + w * 256 + kt * 32 + q * 8];
#pragma unroll
            for (int m = 0; m < 4; ++m)
#pragma unroll
                for (int g = 0; g < 4; ++g)
                    acc[m][g] = __builtin_amdgcn_mfma_f32_16x16x32_bf16(a[m], b[g][kt], acc[m][g], 0, 0, 0);
        }

        __syncthreads();
#pragma unroll
        for (int m = 0; m < 4; ++m)
#pragma unroll
            for (int g = 0; g < 4; ++g)
                red[m][w][g][u] = acc[m][g];
        __syncthreads();
        f32x4 gate[4];
#pragma unroll
        for (int g = 0; g < 4; ++g) {
            gate[g] = red[w][0][g][u];
#pragma unroll
            for (int w2 = 1; w2 < 4; ++w2)
                gate[g] += red[w][w2][g][u];
        }

#pragma unroll
        for (int r = 0; r < 4; ++r) {
            float F = sigm(gate[0][r] + bf2f(xg[0][r]));
            float I = sigm(gate[1][r] + bf2f(xg[1][r]));
            float Cd = tanhf(gate[2][r] + bf2f(xg[2][r]));
            float O = sigm(gate[3][r] + bf2f(xg[3][r]));
            float cn = F * c[r] + I * Cd;
            c[r] = cn;
            float hf = tanhf(cn) * O;
            int row = w * 16 + q * 4 + r;
            hs[row * 16 + jj] = f2bf(hf);
            if (t == 255) {
                out_h[(size_t)row * 1024 + j0 + jj] = hf;
                out_c[(size_t)row * 1024 + j0 + jj] = cn;
            }
        }
        __syncthreads();

        {
            unsigned long long v = *(const unsigned long long*)&hs[srow_ * 16 + sqtr * 4];
            __hip_atomic_store((unsigned long long*)&H[(size_t)(t * 64 + srow_) * 1024 + j0 + sqtr * 4],
                               v, __ATOMIC_RELAXED, __HIP_MEMORY_SCOPE_AGENT);
        }

        if (t < 255) {
            asm volatile("s_waitcnt vmcnt(0)" ::: "memory");
            __syncthreads();
            if (l == 0)
                __hip_atomic_store(&flags[bid], (unsigned)(t + 1),
                                   __ATOMIC_RELAXED, __HIP_MEMORY_SCOPE_AGENT);
#pragma unroll
            for (int g = 0; g < 4; ++g)
#pragma unroll
                for (int r = 0; r < 4; ++r)
                    xg[g][r] = Xg[(size_t)((t + 1) * 64 + w * 16 + q * 4 + r) * 4096 + g * 1024 + j0 + jj];
            const unsigned tgt = (unsigned)(t + 1);
            unsigned long long wd0 = __builtin_amdgcn_s_memrealtime();
            while (true) {
                unsigned f = __hip_atomic_load(&flags[16 * w + jj], __ATOMIC_RELAXED,
                                               __HIP_MEMORY_SCOPE_AGENT);
                if (__all(f >= tgt)) break;
                if (__builtin_amdgcn_s_memrealtime() - wd0 > WDOG_POLL) break;
                __builtin_amdgcn_s_sleep(4);
            }
            asm volatile("" ::: "memory");
            __builtin_amdgcn_sched_barrier(0);
        }
    }
}

// ================= dispatcher kernel =================
__global__ __launch_bounds__(256, 1) void lstm_scan(
    const unsigned short* __restrict__ Whc, const unsigned short* __restrict__ Xg,
    const unsigned short* __restrict__ h0bf, unsigned short* __restrict__ H,
    const float* __restrict__ c0, float* __restrict__ out_h, float* __restrict__ out_c,
    unsigned int* __restrict__ flags) {
    __shared__ __align__(16) char smem_[67584];   // GO: red[4][8][64] (32KB) | NOGO: red64 64KB + hs 2KB
    __shared__ int s_dec;
    __shared__ int s_allsame;
    const int l = threadIdx.x, w = l >> 6, u = l & 63;
    const int bid = blockIdx.x;

    // ---- residency vote: arrive, decide (bid 0), read decision ----
    if (l == 0) {
        __hip_atomic_fetch_add(&flags[512], 1u, __ATOMIC_RELAXED, __HIP_MEMORY_SCOPE_AGENT);
        unsigned dec = 0;
        if (bid == 0) {
            unsigned long long t0 = __builtin_amdgcn_s_memrealtime();
            while (true) {
                unsigned cnt = __hip_atomic_load(&flags[512], __ATOMIC_RELAXED,
                                                 __HIP_MEMORY_SCOPE_AGENT);
                if (cnt >= 256u) { dec = 1u; break; }
                if (__builtin_amdgcn_s_memrealtime() - t0 > DEC_WAIT) { dec = 2u; break; }
                __builtin_amdgcn_s_sleep(8);
            }
            __hip_atomic_store(&flags[513], dec, __ATOMIC_RELAXED, __HIP_MEMORY_SCOPE_AGENT);
        } else {
            unsigned long long t0 = __builtin_amdgcn_s_memrealtime();
            while (true) {
                dec = __hip_atomic_load(&flags[513], __ATOMIC_RELAXED, __HIP_MEMORY_SCOPE_AGENT);
                if (dec) break;
                if (__builtin_amdgcn_s_memrealtime() - t0 > WDOG_DEC) { dec = 2u; break; }
                __builtin_amdgcn_s_sleep(8);
            }
        }
        s_dec = (int)dec;
    }
    __syncthreads();

    if (s_dec == 1) {
        // ---- GO: all 256 WGs resident. Per-group XCD homogeneity check ----
        const int g = bid & 7, i = bid >> 3;
        unsigned int* xcc = flags + 256;
        unsigned my_xcc;
        asm volatile("s_getreg_b32 %0, hwreg(HW_REG_XCC_ID)" : "=s"(my_xcc));
        if (l == 0)
            __hip_atomic_store(&xcc[bid], 256u | (my_xcc & 255u),
                               __ATOMIC_RELAXED, __HIP_MEMORY_SCOPE_AGENT);
        if (w == 0) {
            unsigned v = 256u;
            unsigned long long wd0 = __builtin_amdgcn_s_memrealtime();
            int timeout = 0;
            while (true) {
                v = (u < 32) ? __hip_atomic_load(&xcc[(u << 3) | g], __ATOMIC_RELAXED,
                                                 __HIP_MEMORY_SCOPE_AGENT)
                             : 257u;
                unsigned long long rdy = __ballot(v >= 256u);
                if (rdy == ~0ull) break;
                if (__builtin_amdgcn_s_memrealtime() - wd0 > WDOG_DEC) { timeout = 1; break; }
                __builtin_amdgcn_s_sleep(8);
            }
            unsigned first = __shfl(v, 0);
            int same = ((u < 32) ? (v == first) : 1) ? 1 : 0;
            unsigned long long m = __ballot(same);
            if (u == 0) s_allsame = (!timeout && m == ~0ull) ? 1 : 0;
        }
        __syncthreads();

        f32x4 (*red)[8][64] = (f32x4(*)[8][64])smem_;
        if (s_allsame)
            scan_go<1>(g, i, l, w, u, Whc, Xg, h0bf, H, c0, out_h, out_c, flags, red);
        else
            scan_go<0>(g, i, l, w, u, Whc, Xg, h0bf, H, c0, out_h, out_c, flags, red);
    } else {
        // ---- NOGO: bids >= 64 exit (frees CUs for stragglers); bids < 64 run R5 scan ----
        if (bid >= 64) return;
        f32x4 (*red64)[4][4][64] = (f32x4(*)[4][4][64])smem_;
        unsigned short* hs = (unsigned short*)(smem_ + 65536);
        scan64(bid, l, w, u, Whc, Xg, h0bf, H, c0, out_h, out_c, flags, red64, hs);
    }
}

// ---------- launch ----------
extern "C" void kernel_launch(void* const* d_in, const int* in_sizes, int n_in,
                              void* d_out, int out_size, void* d_ws, size_t ws_size,
                              hipStream_t stream) {
    const float* steps = (const float*)d_in[0];
    const float* h0 = (const float*)d_in[1];
    const float* c0 = (const float*)d_in[2];
    const float* Wfx = (const float*)d_in[3];
    const float* Wfh = (const float*)d_in[4];
    const float* bf_ = (const float*)d_in[5];
    const float* Wix = (const float*)d_in[6];
    const float* Wih = (const float*)d_in[7];
    const float* bi_ = (const float*)d_in[8];
    const float* Wcx = (const float*)d_in[9];
    const float* Wch = (const float*)d_in[10];
    const float* bc_ = (const float*)d_in[11];
    const float* Wox = (const float*)d_in[12];
    const float* Woh = (const float*)d_in[13];
    const float* bo_ = (const float*)d_in[14];
    const float* Wy = (const float*)d_in[15];
    const float* by_ = (const float*)d_in[16];

    char* ws = (char*)d_ws;
    unsigned short* Xbf = (unsigned short*)(ws + 0L);           //  33,554,432 B
    unsigned short* Xg  = (unsigned short*)(ws + 33554432L);    // 134,217,728 B
    unsigned short* H   = (unsigned short*)(ws + 167772160L);   //  33,554,432 B
    unsigned short* Wx  = (unsigned short*)(ws + 201326592L);   //   8,388,608 B
    unsigned short* Wh  = (unsigned short*)(ws + 209715200L);   //   8,388,608 B
    unsigned short* Wyt = (unsigned short*)(ws + 218103808L);   //   2,097,152 B
    float* bcat         = (float*)(ws + 220200960L);            //      16,384 B
    unsigned short* hbuf0 = (unsigned short*)(ws + 220217344L); //     131,072 B
    unsigned int* flags = (unsigned int*)(ws + 220348416L);     //       4,096 B

    float* out_y = (float*)d_out;
    float* out_h = out_y + 16777216L;
    float* out_c = out_h + 65536L;

    // 1. convert X to bf16
    conv_bf16<<<2048, 256, 0, stream>>>((const float4*)steps, (ushort4*)Xbf, 4194304);

    // 2. transpose-pack all weights to bf16 [N][K]
    PackArgs pa;
    pa.src[0] = Wfx; pa.src[1] = Wix; pa.src[2] = Wcx; pa.src[3] = Wox;
    pa.src[4] = Wfh; pa.src[5] = Wih; pa.src[6] = Wch; pa.src[7] = Woh;
    pa.src[8] = Wy;
    pack_w<<<dim3(32, 32, 9), 256, 0, stream>>>(pa, Wx, Wh, Wyt);

    // 3. small init (h0->bf16, bias concat, flags = 0) — runs every replay
    init_small<<<256, 256, 0, stream>>>(h0, bf_, bi_, bc_, bo_, hbuf0, bcat, flags);

    // 4. Xg = X @ Wxcat + bcat   (M=16384, N=4096, K=1024), bf16 out
    gemm_bt<1><<<dim3(32, 128), 256, 0, stream>>>(Xbf, Wx, bcat, Xg, 16384, 4096, 1024);

    // 5. persistent scan: plain 256-WG launch, on-device residency vote,
    //    GO -> XCD-local groups; NOGO -> proven 64-WG fallback (always correct)
    lstm_scan<<<256, 256, 0, stream>>>(Wh, Xg, hbuf0, H, c0, out_h, out_c, flags);

    // 6. Y = H @ Wy + by  (M=16384, N=1024, K=1024), fp32 out to d_out
    gemm_bt<0><<<dim3(8, 128), 256, 0, stream>>>(H, Wyt, by_, (void*)d_out, 16384, 1024, 1024);
}

// Round 10
// 474472.998 us; speedup vs baseline: 10.1309x; 10.1309x over previous
//
#include <hip/hip_runtime.h>

// ---------- types / helpers ----------
typedef short short8 __attribute__((ext_vector_type(8)));
typedef float f32x4 __attribute__((ext_vector_type(4)));

__device__ __forceinline__ float bf2f(unsigned short s) {
    unsigned int u = ((unsigned int)s) << 16;
    return __builtin_bit_cast(float, u);
}
__device__ __forceinline__ unsigned short f2bf(float f) {
    unsigned int u = __builtin_bit_cast(unsigned int, f);
    u += 0x7fffu + ((u >> 16) & 1u);
    return (unsigned short)(u >> 16);
}
__device__ __forceinline__ float sigm(float x) { return 1.0f / (1.0f + __expf(-x)); }

__device__ __forceinline__ void gload16(const void* g, void* l) {
    __builtin_amdgcn_global_load_lds((const __attribute__((address_space(1))) void*)g,
                                     (__attribute__((address_space(3))) void*)l, 16, 0, 0);
}

// XCD-L2 flag read: invalidate own L1 (local, cheap), then PLAIN load -> forced L2 hit.
// (R9 lesson: sc0-only loads do NOT bypass L1 on gfx950 -> stale-L1 livelock.)
__device__ __forceinline__ unsigned ld_l2(const unsigned* p) {
    unsigned v;
    asm volatile("buffer_inv sc0\n\t"
                 "global_load_dword %0, %1, off\n\t"
                 "s_waitcnt vmcnt(0)"
                 : "=v"(v) : "v"(p) : "memory");
    return v;
}

#define WDOG_POLL 200000ull    // 2 ms (s_memrealtime ~100 MHz) — never fires when healthy
#define WDOG_DEC  2000000ull   // 20 ms
#define DEC_WAIT  10000ull     // 100 us decider patience

// ---------- kernel: fp32 -> bf16 vectorized convert ----------
__global__ void conv_bf16(const float4* __restrict__ src, ushort4* __restrict__ dst, int n4) {
    for (int i = blockIdx.x * blockDim.x + threadIdx.x; i < n4; i += gridDim.x * blockDim.x) {
        float4 v = src[i];
        ushort4 o;
        o.x = f2bf(v.x); o.y = f2bf(v.y); o.z = f2bf(v.z); o.w = f2bf(v.w);
        dst[i] = o;
    }
}

// ---------- kernel: transpose+convert 9 weight matrices to bf16 [N][K] ----------
struct PackArgs { const float* src[9]; };

__global__ __launch_bounds__(256) void pack_w(PackArgs pa,
                                              unsigned short* __restrict__ Wx,
                                              unsigned short* __restrict__ Wh,
                                              unsigned short* __restrict__ Wyt) {
    __shared__ float tile[32][33];
    const int z = blockIdx.z;
    const float* S = pa.src[z];
    unsigned short* D = (z < 4) ? Wx + (long)z * 1048576
                                : (z < 8) ? Wh + (long)(z - 4) * 1048576
                                          : Wyt;
    const int tx = threadIdx.x & 31, ty = threadIdx.x >> 5;
    const int rb = blockIdx.y * 32, cb = blockIdx.x * 32;
#pragma unroll
    for (int rr = 0; rr < 4; ++rr) {
        int r = ty + rr * 8;
        tile[r][tx] = S[(long)(rb + r) * 1024 + cb + tx];
    }
    __syncthreads();
#pragma unroll
    for (int rr = 0; rr < 4; ++rr) {
        int r = ty + rr * 8;
        D[(long)(cb + r) * 1024 + rb + tx] = f2bf(tile[tx][r]);
    }
}

// ---------- kernel: small init (bias concat, h0->bf16, flags=0) ----------
__global__ void init_small(const float* __restrict__ h0,
                           const float* __restrict__ bf_, const float* __restrict__ bi_,
                           const float* __restrict__ bc_, const float* __restrict__ bo_,
                           unsigned short* __restrict__ hbuf0,
                           float* __restrict__ bcat, unsigned int* __restrict__ flags) {
    int i = blockIdx.x * blockDim.x + threadIdx.x;
    if (i < 1024) flags[i] = 0u;   // step flags[0..256) | xcc[256..512) | arrive[512] | dec[513]
    if (i < 65536) hbuf0[i] = f2bf(h0[i]);
    if (i < 4096) {
        const float* bs = (i < 1024) ? bf_ : (i < 2048) ? bi_ : (i < 3072) ? bc_ : bo_;
        bcat[i] = bs[i & 1023];
    }
}

// ---------- kernel: 128x128 bf16 MFMA GEMM, A[M][K] x B^T[N][K] + bias ----------
template <int OUT_BF16>
__global__ __launch_bounds__(256) void gemm_bt(const unsigned short* __restrict__ A,
                                               const unsigned short* __restrict__ B,
                                               const float* __restrict__ bias,
                                               void* __restrict__ Cout,
                                               int M, int N, int K) {
    __shared__ unsigned short As[128 * 32];
    __shared__ unsigned short Bs[128 * 32];
    const int l = threadIdx.x;
    const int w = l >> 6, u = l & 63;
    const int wr = w >> 1, wc = w & 1;
    const long rowbase = (long)blockIdx.y * 128;
    const long colbase = (long)blockIdx.x * 128;

    f32x4 acc[4][4] = {};

    const int srow = l >> 2;
    const int sunit = l & 3;

    for (int k0 = 0; k0 < K; k0 += 32) {
#pragma unroll
        for (int i = 0; i < 2; ++i) {
            int row = i * 64 + srow;
            int su = sunit ^ (row & 3);
            gload16(&A[(rowbase + row) * K + k0 + su * 8], &As[i * 2048 + l * 8]);
            gload16(&B[(colbase + row) * K + k0 + su * 8], &Bs[i * 2048 + l * 8]);
        }
        __syncthreads();
        short8 a[4], b[4];
#pragma unroll
        for (int mi = 0; mi < 4; ++mi) {
            int row = wr * 64 + mi * 16 + (u & 15);
            a[mi] = *(const short8*)&As[row * 32 + (((u >> 4) ^ (row & 3))) * 8];
        }
#pragma unroll
        for (int ni = 0; ni < 4; ++ni) {
            int row = wc * 64 + ni * 16 + (u & 15);
            b[ni] = *(const short8*)&Bs[row * 32 + (((u >> 4) ^ (row & 3))) * 8];
        }
#pragma unroll
        for (int mi = 0; mi < 4; ++mi)
#pragma unroll
            for (int ni = 0; ni < 4; ++ni)
                acc[mi][ni] = __builtin_amdgcn_mfma_f32_16x16x32_bf16(a[mi], b[ni], acc[mi][ni], 0, 0, 0);
        __syncthreads();
    }

#pragma unroll
    for (int mi = 0; mi < 4; ++mi) {
#pragma unroll
        for (int ni = 0; ni < 4; ++ni) {
#pragma unroll
            for (int r = 0; r < 4; ++r) {
                long row = rowbase + wr * 64 + mi * 16 + (u >> 4) * 4 + r;
                long col = colbase + wc * 64 + ni * 16 + (u & 15);
                float v = acc[mi][ni][r] + bias[col];
                if (OUT_BF16)
                    ((unsigned short*)Cout)[row * N + col] = f2bf(v);
                else
                    ((float*)Cout)[row * N + col] = v;
            }
        }
    }
}

// ================= GO world: batch-partitioned XCD-local scan (256 WGs) =================
// Group g = {bid: bid%8==g} (32 WGs) owns batch rows [8g,8g+8). WG i=bid>>3 owns hidden
// cols [32i,32i+32) (=128 gate cols). Wave w = K-slice [256w,..+256). Weights in VGPRs.
template <int FAST>
__device__ __forceinline__ void scan_go(
    int g, int i, int l, int w, int u,
    const unsigned short* __restrict__ Whc, const unsigned short* __restrict__ Xg,
    const unsigned short* __restrict__ h0bf, unsigned short* __restrict__ H,
    const float* __restrict__ c0, float* __restrict__ out_h, float* __restrict__ out_c,
    unsigned int* __restrict__ flags, f32x4 (*red)[8][64]) {

    const int rho = l >> 5, chi = l & 31;
    const int arow = u & 15;
    const int kofs = (u >> 4) * 8;

    short8 b[8][8];
#pragma unroll
    for (int n = 0; n < 8; ++n)
#pragma unroll
        for (int kt = 0; kt < 8; ++kt)
            b[n][kt] = *(const short8*)&Whc[(size_t)((n >> 1) * 1024 + 32 * i + 16 * (n & 1) + arow) * 1024
                                            + w * 256 + kt * 32 + kofs];

    float c = c0[(size_t)(8 * g + rho) * 1024 + 32 * i + chi];

    unsigned short xg[4];
#pragma unroll
    for (int ga = 0; ga < 4; ++ga)
        xg[ga] = Xg[(size_t)(8 * g + rho) * 4096 + ga * 1024 + 32 * i + chi];

    const short8 az = {};

#pragma unroll 1
    for (int t = 0; t < 256; ++t) {
        const unsigned short* hp = t ? (H + (size_t)(t - 1) * 65536 + 8 * g * 1024)
                                     : (h0bf + 8 * g * 1024);
        const unsigned short* ab = hp + (size_t)arow * 1024 + w * 256 + kofs;

        f32x4 acc[8] = {};
#pragma unroll
        for (int kt = 0; kt < 8; ++kt) {
            short8 a = (arow < 8) ? *(const short8*)(ab + kt * 32) : az;
#pragma unroll
            for (int n = 0; n < 8; ++n)
                acc[n] = __builtin_amdgcn_mfma_f32_16x16x32_bf16(a, b[n][kt], acc[n], 0, 0, 0);
        }

#pragma unroll
        for (int n = 0; n < 8; ++n)
            red[w][n][u] = acc[n];
        __syncthreads();

        float pre[4];
#pragma unroll
        for (int ga = 0; ga < 4; ++ga) {
            int n = ga * 2 + (chi >> 4);
            int sl = ((rho >> 2) << 4) + (chi & 15);
            int rg = rho & 3;
            const float* r0 = (const float*)&red[0][n][sl];
            const float* r1 = (const float*)&red[1][n][sl];
            const float* r2 = (const float*)&red[2][n][sl];
            const float* r3 = (const float*)&red[3][n][sl];
            pre[ga] = r0[rg] + r1[rg] + r2[rg] + r3[rg] + bf2f(xg[ga]);
        }
        float F = sigm(pre[0]);
        float I = sigm(pre[1]);
        float Cd = tanhf(pre[2]);
        float O = sigm(pre[3]);
        float cn = F * c + I * Cd;
        c = cn;
        float hf = tanhf(cn) * O;

        const size_t hidx = (size_t)(t * 64 + 8 * g + rho) * 1024 + 32 * i + chi;
        if (FAST) {
            H[hidx] = f2bf(hf);  // plain store: write-through -> own XCD L2 (consumers same XCD)
        } else {
            __hip_atomic_store(&H[hidx], f2bf(hf), __ATOMIC_RELAXED, __HIP_MEMORY_SCOPE_AGENT);
        }
        if (t == 255) {
            out_h[(size_t)(8 * g + rho) * 1024 + 32 * i + chi] = hf;
            out_c[(size_t)(8 * g + rho) * 1024 + 32 * i + chi] = cn;
        }

        if (t < 255) {
            asm volatile("s_waitcnt vmcnt(0)" ::: "memory");  // h stores committed to L2
            __syncthreads();
            if (l == 0) {
                if (FAST)
                    *(volatile unsigned*)&flags[g * 32 + i] = (unsigned)(t + 1);  // L2-resident flag
                else
                    __hip_atomic_store(&flags[g * 32 + i], (unsigned)(t + 1),
                                       __ATOMIC_RELAXED, __HIP_MEMORY_SCOPE_AGENT);
            }
            // per-wave poll: the 8 producers of this wave's K-slice (group WGs 8w..8w+7)
            const unsigned tgt = (unsigned)(t + 1);
            unsigned long long wd0 = __builtin_amdgcn_s_memrealtime();
            while (true) {
                unsigned f;
                if (FAST)
                    f = ld_l2(&flags[g * 32 + 8 * w + (u & 7)]);   // L1-inv + plain load = L2 read
                else
                    f = (u < 8) ? __hip_atomic_load(&flags[g * 32 + 8 * w + u],
                                                    __ATOMIC_RELAXED, __HIP_MEMORY_SCOPE_AGENT)
                                : tgt;
                if (__all(f >= tgt)) break;
                if (__builtin_amdgcn_s_memrealtime() - wd0 > WDOG_POLL) break;  // bug -> slow-but-correct
                __builtin_amdgcn_s_sleep(1);
            }
            asm volatile("" ::: "memory");
            __builtin_amdgcn_sched_barrier(0);
            // next-step Xg prefetch AFTER poll: latency hides under next GEMM (xg used in epilogue)
#pragma unroll
            for (int ga = 0; ga < 4; ++ga)
                xg[ga] = Xg[(size_t)((t + 1) * 64 + 8 * g + rho) * 4096 + ga * 1024 + 32 * i + chi];
        }
    }
}

// ================= NOGO world: proven R5 64-WG scan (bids 0..63) =================
__device__ __forceinline__ void scan64(
    int bid, int l, int w, int u,
    const unsigned short* __restrict__ Whc, const unsigned short* __restrict__ Xg,
    const unsigned short* __restrict__ h0bf, unsigned short* __restrict__ H,
    const float* __restrict__ c0, float* __restrict__ out_h, float* __restrict__ out_c,
    unsigned int* __restrict__ flags, f32x4 (*red)[4][4][64], unsigned short* hs) {

    const int j0 = bid * 16;
    const int jj = u & 15, q = u >> 4;

    short8 b[4][8];
#pragma unroll
    for (int g = 0; g < 4; ++g)
#pragma unroll
        for (int kt = 0; kt < 8; ++kt)
            b[g][kt] = *(const short8*)&Whc[(size_t)(g * 1024 + j0 + jj) * 1024 + w * 256 + kt * 32 + q * 8];

    float c[4];
#pragma unroll
    for (int r = 0; r < 4; ++r)
        c[r] = c0[(size_t)(w * 16 + q * 4 + r) * 1024 + j0 + jj];

    unsigned short xg[4][4];
#pragma unroll
    for (int g = 0; g < 4; ++g)
#pragma unroll
        for (int r = 0; r < 4; ++r)
            xg[g][r] = Xg[(size_t)(w * 16 + q * 4 + r) * 4096 + g * 1024 + j0 + jj];

    const int srow_ = l >> 2, sqtr = l & 3;

#pragma unroll 1
    for (int t = 0; t < 256; ++t) {
        const unsigned short* hp = t ? (H + (size_t)(t - 1) * 65536) : h0bf;

        f32x4 acc[4][4] = {};
#pragma unroll
        for (int kt = 0; kt < 8; ++kt) {
            short8 a[4];
#pragma unroll
            for (int m = 0; m < 4; ++m)
                a[m] = *(const short8*)&hp[(size_t)(m * 16 + jj) * 1024 + w * 256 + kt * 32 + q * 8];
#pragma unroll
            for (int m = 0; m < 4; ++m)
#pragma unroll
                for (int g = 0; g < 4; ++g)
                    acc[m][g] = __builtin_amdgcn_mfma_f32_16x16x32_bf16(a[m], b[g][kt], acc[m][g], 0, 0, 0);
        }

        __syncthreads();
#pragma unroll
        for (int m = 0; m < 4; ++m)
#pragma unroll
            for (int g = 0; g < 4; ++g)
                red[m][w][g][u] = acc[m][g];
        __syncthreads();
        f32x4 gate[4];
#pragma unroll
        for (int g = 0; g < 4; ++g) {
            gate[g] = red[w][0][g][u];
#pragma unroll
            for (int w2 = 1; w2 < 4; ++w2)
                gate[g] += red[w][w2][g][u];
        }

#pragma unroll
        for (int r = 0; r < 4; ++r) {
            float F = sigm(gate[0][r] + bf2f(xg[0][r]));
            float I = sigm(gate[1][r] + bf2f(xg[1][r]));
            float Cd = tanhf(gate[2][r] + bf2f(xg[2][r]));
            float O = sigm(gate[3][r] + bf2f(xg[3][r]));
            float cn = F * c[r] + I * Cd;
            c[r] = cn;
            float hf = tanhf(cn) * O;
            int row = w * 16 + q * 4 + r;
            hs[row * 16 + jj] = f2bf(hf);
            if (t == 255) {
                out_h[(size_t)row * 1024 + j0 + jj] = hf;
                out_c[(size_t)row * 1024 + j0 + jj] = cn;
            }
        }
        __syncthreads();

        {
            unsigned long long v = *(const unsigned long long*)&hs[srow_ * 16 + sqtr * 4];
            __hip_atomic_store((unsigned long long*)&H[(size_t)(t * 64 + srow_) * 1024 + j0 + sqtr * 4],
                               v, __ATOMIC_RELAXED, __HIP_MEMORY_SCOPE_AGENT);
        }

        if (t < 255) {
            asm volatile("s_waitcnt vmcnt(0)" ::: "memory");
            __syncthreads();
            if (l == 0)
                __hip_atomic_store(&flags[bid], (unsigned)(t + 1),
                                   __ATOMIC_RELAXED, __HIP_MEMORY_SCOPE_AGENT);
#pragma unroll
            for (int g = 0; g < 4; ++g)
#pragma unroll
                for (int r = 0; r < 4; ++r)
                    xg[g][r] = Xg[(size_t)((t + 1) * 64 + w * 16 + q * 4 + r) * 4096 + g * 1024 + j0 + jj];
            const unsigned tgt = (unsigned)(t + 1);
            unsigned long long wd0 = __builtin_amdgcn_s_memrealtime();
            while (true) {
                unsigned f = __hip_atomic_load(&flags[16 * w + jj], __ATOMIC_RELAXED,
                                               __HIP_MEMORY_SCOPE_AGENT);
                if (__all(f >= tgt)) break;
                if (__builtin_amdgcn_s_memrealtime() - wd0 > WDOG_POLL) break;
                __builtin_amdgcn_s_sleep(4);
            }
            asm volatile("" ::: "memory");
            __builtin_amdgcn_sched_barrier(0);
        }
    }
}

// ================= dispatcher kernel =================
__global__ __launch_bounds__(256, 1) void lstm_scan(
    const unsigned short* __restrict__ Whc, const unsigned short* __restrict__ Xg,
    const unsigned short* __restrict__ h0bf, unsigned short* __restrict__ H,
    const float* __restrict__ c0, float* __restrict__ out_h, float* __restrict__ out_c,
    unsigned int* __restrict__ flags) {
    __shared__ __align__(16) char smem_[67584];   // GO: red[4][8][64] 32KB | NOGO: 64KB + hs 2KB
    __shared__ int s_dec;
    __shared__ int s_allsame;
    const int l = threadIdx.x, w = l >> 6, u = l & 63;
    const int bid = blockIdx.x;

    // ---- residency vote: arrive, decide (bid 0), read decision ----
    if (l == 0) {
        __hip_atomic_fetch_add(&flags[512], 1u, __ATOMIC_RELAXED, __HIP_MEMORY_SCOPE_AGENT);
        unsigned dec = 0;
        if (bid == 0) {
            unsigned long long t0 = __builtin_amdgcn_s_memrealtime();
            while (true) {
                unsigned cnt = __hip_atomic_load(&flags[512], __ATOMIC_RELAXED,
                                                 __HIP_MEMORY_SCOPE_AGENT);
                if (cnt >= 256u) { dec = 1u; break; }
                if (__builtin_amdgcn_s_memrealtime() - t0 > DEC_WAIT) { dec = 2u; break; }
                __builtin_amdgcn_s_sleep(8);
            }
            __hip_atomic_store(&flags[513], dec, __ATOMIC_RELAXED, __HIP_MEMORY_SCOPE_AGENT);
        } else {
            unsigned long long t0 = __builtin_amdgcn_s_memrealtime();
            while (true) {
                dec = __hip_atomic_load(&flags[513], __ATOMIC_RELAXED, __HIP_MEMORY_SCOPE_AGENT);
                if (dec) break;
                if (__builtin_amdgcn_s_memrealtime() - t0 > WDOG_DEC) { dec = 2u; break; }
                __builtin_amdgcn_s_sleep(8);
            }
        }
        s_dec = (int)dec;
    }
    __syncthreads();

    if (s_dec == 1) {
        // ---- GO: all 256 WGs resident. Per-group XCD homogeneity check ----
        const int g = bid & 7, i = bid >> 3;
        unsigned int* xcc = flags + 256;
        unsigned my_xcc;
        asm volatile("s_getreg_b32 %0, hwreg(HW_REG_XCC_ID)" : "=s"(my_xcc));
        if (l == 0)
            __hip_atomic_store(&xcc[bid], 256u | (my_xcc & 255u),
                               __ATOMIC_RELAXED, __HIP_MEMORY_SCOPE_AGENT);
        if (w == 0) {
            unsigned v = 256u;
            unsigned long long wd0 = __builtin_amdgcn_s_memrealtime();
            int timeout = 0;
            while (true) {
                v = (u < 32) ? __hip_atomic_load(&xcc[(u << 3) | g], __ATOMIC_RELAXED,
                                                 __HIP_MEMORY_SCOPE_AGENT)
                             : 257u;
                unsigned long long rdy = __ballot(v >= 256u);
                if (rdy == ~0ull) break;
                if (__builtin_amdgcn_s_memrealtime() - wd0 > WDOG_DEC) { timeout = 1; break; }
                __builtin_amdgcn_s_sleep(8);
            }
            unsigned first = __shfl(v, 0);
            int same = ((u < 32) ? (v == first) : 1) ? 1 : 0;
            unsigned long long m = __ballot(same);
            if (u == 0) s_allsame = (!timeout && m == ~0ull) ? 1 : 0;
        }
        __syncthreads();

        f32x4 (*red)[8][64] = (f32x4(*)[8][64])smem_;
        if (s_allsame)
            scan_go<1>(g, i, l, w, u, Whc, Xg, h0bf, H, c0, out_h, out_c, flags, red);
        else
            scan_go<0>(g, i, l, w, u, Whc, Xg, h0bf, H, c0, out_h, out_c, flags, red);
    } else {
        // ---- NOGO: bids >= 64 exit (frees CUs); bids < 64 run proven R5 scan ----
        if (bid >= 64) return;
        f32x4 (*red64)[4][4][64] = (f32x4(*)[4][4][64])smem_;
        unsigned short* hs = (unsigned short*)(smem_ + 65536);
        scan64(bid, l, w, u, Whc, Xg, h0bf, H, c0, out_h, out_c, flags, red64, hs);
    }
}

// ---------- launch ----------
extern "C" void kernel_launch(void* const* d_in, const int* in_sizes, int n_in,
                              void* d_out, int out_size, void* d_ws, size_t ws_size,
                              hipStream_t stream) {
    const float* steps = (const float*)d_in[0];
    const float* h0 = (const float*)d_in[1];
    const float* c0 = (const float*)d_in[2];
    const float* Wfx = (const float*)d_in[3];
    const float* Wfh = (const float*)d_in[4];
    const float* bf_ = (const float*)d_in[5];
    const float* Wix = (const float*)d_in[6];
    const float* Wih = (const float*)d_in[7];
    const float* bi_ = (const float*)d_in[8];
    const float* Wcx = (const float*)d_in[9];
    const float* Wch = (const float*)d_in[10];
    const float* bc_ = (const float*)d_in[11];
    const float* Wox = (const float*)d_in[12];
    const float* Woh = (const float*)d_in[13];
    const float* bo_ = (const float*)d_in[14];
    const float* Wy = (const float*)d_in[15];
    const float* by_ = (const float*)d_in[16];

    char* ws = (char*)d_ws;
    unsigned short* Xbf = (unsigned short*)(ws + 0L);           //  33,554,432 B
    unsigned short* Xg  = (unsigned short*)(ws + 33554432L);    // 134,217,728 B
    unsigned short* H   = (unsigned short*)(ws + 167772160L);   //  33,554,432 B
    unsigned short* Wx  = (unsigned short*)(ws + 201326592L);   //   8,388,608 B
    unsigned short* Wh  = (unsigned short*)(ws + 209715200L);   //   8,388,608 B
    unsigned short* Wyt = (unsigned short*)(ws + 218103808L);   //   2,097,152 B
    float* bcat         = (float*)(ws + 220200960L);            //      16,384 B
    unsigned short* hbuf0 = (unsigned short*)(ws + 220217344L); //     131,072 B
    unsigned int* flags = (unsigned int*)(ws + 220348416L);     //       4,096 B

    float* out_y = (float*)d_out;
    float* out_h = out_y + 16777216L;
    float* out_c = out_h + 65536L;

    // 1. convert X to bf16
    conv_bf16<<<2048, 256, 0, stream>>>((const float4*)steps, (ushort4*)Xbf, 4194304);

    // 2. transpose-pack all weights to bf16 [N][K]
    PackArgs pa;
    pa.src[0] = Wfx; pa.src[1] = Wix; pa.src[2] = Wcx; pa.src[3] = Wox;
    pa.src[4] = Wfh; pa.src[5] = Wih; pa.src[6] = Wch; pa.src[7] = Woh;
    pa.src[8] = Wy;
    pack_w<<<dim3(32, 32, 9), 256, 0, stream>>>(pa, Wx, Wh, Wyt);

    // 3. small init (h0->bf16, bias concat, flags = 0) — runs every replay
    init_small<<<256, 256, 0, stream>>>(h0, bf_, bi_, bc_, bo_, hbuf0, bcat, flags);

    // 4. Xg = X @ Wxcat + bcat   (M=16384, N=4096, K=1024), bf16 out
    gemm_bt<1><<<dim3(32, 128), 256, 0, stream>>>(Xbf, Wx, bcat, Xg, 16384, 4096, 1024);

    // 5. persistent scan: plain 256-WG launch, residency vote, XCD-local FAST path
    lstm_scan<<<256, 256, 0, stream>>>(Wh, Xg, hbuf0, H, c0, out_h, out_c, flags);

    // 6. Y = H @ Wy + by  (M=16384, N=1024, K=1024), fp32 out to d_out
    gemm_bt<0><<<dim3(8, 128), 256, 0, stream>>>(H, Wyt, by_, (void*)d_out, 16384, 1024, 1024);
}

// Round 11
// 1958.192 us; speedup vs baseline: 2454.7310x; 242.3016x over previous
//
#include <hip/hip_runtime.h>

// ---------- types / helpers ----------
typedef short short8 __attribute__((ext_vector_type(8)));
typedef float f32x4 __attribute__((ext_vector_type(4)));

__device__ __forceinline__ float bf2f(unsigned short s) {
    unsigned int u = ((unsigned int)s) << 16;
    return __builtin_bit_cast(float, u);
}
__device__ __forceinline__ unsigned short f2bf(float f) {
    unsigned int u = __builtin_bit_cast(unsigned int, f);
    u += 0x7fffu + ((u >> 16) & 1u);
    return (unsigned short)(u >> 16);
}
__device__ __forceinline__ float sigm(float x) { return 1.0f / (1.0f + __expf(-x)); }

__device__ __forceinline__ void gload16(const void* g, void* l) {
    __builtin_amdgcn_global_load_lds((const __attribute__((address_space(1))) void*)g,
                                     (__attribute__((address_space(3))) void*)l, 16, 0, 0);
}

// No-sc global atomics execute at the local XCD L2 and always bypass L1 (both sides).
// (R9/R10 lesson: plain/sc0 loads and buffer_inv cannot reliably observe another CU's
// plain store on gfx950; atomics can.)
__device__ __forceinline__ void at_swap32(unsigned* p, unsigned v) {
    asm volatile("global_atomic_swap %0, %1, off" :: "v"(p), "v"(v) : "memory");
}
__device__ __forceinline__ unsigned at_poll(unsigned* p) {
    unsigned v;
    asm volatile("global_atomic_add %0, %1, %2, off sc0\n\ts_waitcnt vmcnt(0)"
                 : "=v"(v) : "v"(p), "v"(0u) : "memory");
    return v;
}

#define WDOG_POLL 200000ull    // 2 ms — never fires when healthy; bug -> slow-but-correct
#define WDOG_DEC  2000000ull   // 20 ms
#define DEC_WAIT  10000ull     // 100 us decider patience

// ---------- kernel: fp32 -> bf16 vectorized convert ----------
__global__ void conv_bf16(const float4* __restrict__ src, ushort4* __restrict__ dst, int n4) {
    for (int i = blockIdx.x * blockDim.x + threadIdx.x; i < n4; i += gridDim.x * blockDim.x) {
        float4 v = src[i];
        ushort4 o;
        o.x = f2bf(v.x); o.y = f2bf(v.y); o.z = f2bf(v.z); o.w = f2bf(v.w);
        dst[i] = o;
    }
}

// ---------- kernel: transpose+convert 9 weight matrices to bf16 [N][K] ----------
struct PackArgs { const float* src[9]; };

__global__ __launch_bounds__(256) void pack_w(PackArgs pa,
                                              unsigned short* __restrict__ Wx,
                                              unsigned short* __restrict__ Wh,
                                              unsigned short* __restrict__ Wyt) {
    __shared__ float tile[32][33];
    const int z = blockIdx.z;
    const float* S = pa.src[z];
    unsigned short* D = (z < 4) ? Wx + (long)z * 1048576
                                : (z < 8) ? Wh + (long)(z - 4) * 1048576
                                          : Wyt;
    const int tx = threadIdx.x & 31, ty = threadIdx.x >> 5;
    const int rb = blockIdx.y * 32, cb = blockIdx.x * 32;
#pragma unroll
    for (int rr = 0; rr < 4; ++rr) {
        int r = ty + rr * 8;
        tile[r][tx] = S[(long)(rb + r) * 1024 + cb + tx];
    }
    __syncthreads();
#pragma unroll
    for (int rr = 0; rr < 4; ++rr) {
        int r = ty + rr * 8;
        D[(long)(cb + r) * 1024 + rb + tx] = f2bf(tile[tx][r]);
    }
}

// ---------- kernel: small init (bias concat, h0->bf16, flags=0) ----------
__global__ void init_small(const float* __restrict__ h0,
                           const float* __restrict__ bf_, const float* __restrict__ bi_,
                           const float* __restrict__ bc_, const float* __restrict__ bo_,
                           unsigned short* __restrict__ hbuf0,
                           float* __restrict__ bcat, unsigned int* __restrict__ flags) {
    int i = blockIdx.x * blockDim.x + threadIdx.x;
    if (i < 1024) flags[i] = 0u;   // step flags[0..256) | xcc[256..512) | arrive[512] | dec[513]
    if (i < 65536) hbuf0[i] = f2bf(h0[i]);
    if (i < 4096) {
        const float* bs = (i < 1024) ? bf_ : (i < 2048) ? bi_ : (i < 3072) ? bc_ : bo_;
        bcat[i] = bs[i & 1023];
    }
}

// ---------- kernel: 128x128 bf16 MFMA GEMM, A[M][K] x B^T[N][K] + bias ----------
template <int OUT_BF16>
__global__ __launch_bounds__(256) void gemm_bt(const unsigned short* __restrict__ A,
                                               const unsigned short* __restrict__ B,
                                               const float* __restrict__ bias,
                                               void* __restrict__ Cout,
                                               int M, int N, int K) {
    __shared__ unsigned short As[128 * 32];
    __shared__ unsigned short Bs[128 * 32];
    const int l = threadIdx.x;
    const int w = l >> 6, u = l & 63;
    const int wr = w >> 1, wc = w & 1;
    const long rowbase = (long)blockIdx.y * 128;
    const long colbase = (long)blockIdx.x * 128;

    f32x4 acc[4][4] = {};

    const int srow = l >> 2;
    const int sunit = l & 3;

    for (int k0 = 0; k0 < K; k0 += 32) {
#pragma unroll
        for (int i = 0; i < 2; ++i) {
            int row = i * 64 + srow;
            int su = sunit ^ (row & 3);
            gload16(&A[(rowbase + row) * K + k0 + su * 8], &As[i * 2048 + l * 8]);
            gload16(&B[(colbase + row) * K + k0 + su * 8], &Bs[i * 2048 + l * 8]);
        }
        __syncthreads();
        short8 a[4], b[4];
#pragma unroll
        for (int mi = 0; mi < 4; ++mi) {
            int row = wr * 64 + mi * 16 + (u & 15);
            a[mi] = *(const short8*)&As[row * 32 + (((u >> 4) ^ (row & 3))) * 8];
        }
#pragma unroll
        for (int ni = 0; ni < 4; ++ni) {
            int row = wc * 64 + ni * 16 + (u & 15);
            b[ni] = *(const short8*)&Bs[row * 32 + (((u >> 4) ^ (row & 3))) * 8];
        }
#pragma unroll
        for (int mi = 0; mi < 4; ++mi)
#pragma unroll
            for (int ni = 0; ni < 4; ++ni)
                acc[mi][ni] = __builtin_amdgcn_mfma_f32_16x16x32_bf16(a[mi], b[ni], acc[mi][ni], 0, 0, 0);
        __syncthreads();
    }

#pragma unroll
    for (int mi = 0; mi < 4; ++mi) {
#pragma unroll
        for (int ni = 0; ni < 4; ++ni) {
#pragma unroll
            for (int r = 0; r < 4; ++r) {
                long row = rowbase + wr * 64 + mi * 16 + (u >> 4) * 4 + r;
                long col = colbase + wc * 64 + ni * 16 + (u & 15);
                float v = acc[mi][ni][r] + bias[col];
                if (OUT_BF16)
                    ((unsigned short*)Cout)[row * N + col] = f2bf(v);
                else
                    ((float*)Cout)[row * N + col] = v;
            }
        }
    }
}

// ================= GO world: batch-partitioned XCD-local scan (256 WGs) =================
// Group g = {bid: bid%8==g} (32 WGs) owns batch rows [8g,8g+8). WG i=bid>>3 owns hidden
// cols [32i,32i+32) (=128 gate cols). Wave w = K-slice [256w,..+256). Weights in VGPRs.
// FAST: h publish + flag + poll all via NO-SC GLOBAL ATOMICS (execute in local XCD L2,
// bypass L1 on both sides). Data reads: plain cold loads (hit L2 dirty lines).
template <int FAST>
__device__ __forceinline__ void scan_go(
    int g, int i, int l, int w, int u,
    const unsigned short* __restrict__ Whc, const unsigned short* __restrict__ Xg,
    const unsigned short* __restrict__ h0bf, unsigned short* __restrict__ H,
    const float* __restrict__ c0, float* __restrict__ out_h, float* __restrict__ out_c,
    unsigned int* __restrict__ flags, f32x4 (*red)[8][64]) {

    const int rho = l >> 5, chi = l & 31;
    const int arow = u & 15;
    const int kofs = (u >> 4) * 8;

    short8 b[8][8];
#pragma unroll
    for (int n = 0; n < 8; ++n)
#pragma unroll
        for (int kt = 0; kt < 8; ++kt)
            b[n][kt] = *(const short8*)&Whc[(size_t)((n >> 1) * 1024 + 32 * i + 16 * (n & 1) + arow) * 1024
                                            + w * 256 + kt * 32 + kofs];

    float c = c0[(size_t)(8 * g + rho) * 1024 + 32 * i + chi];

    unsigned short xg[4];
#pragma unroll
    for (int ga = 0; ga < 4; ++ga)
        xg[ga] = Xg[(size_t)(8 * g + rho) * 4096 + ga * 1024 + 32 * i + chi];

    const short8 az = {};

#pragma unroll 1
    for (int t = 0; t < 256; ++t) {
        const unsigned short* hp = t ? (H + (size_t)(t - 1) * 65536 + 8 * g * 1024)
                                     : (h0bf + 8 * g * 1024);
        const unsigned short* ab = hp + (size_t)arow * 1024 + w * 256 + kofs;

        f32x4 acc[8] = {};
#pragma unroll
        for (int kt = 0; kt < 8; ++kt) {
            short8 a = (arow < 8) ? *(const short8*)(ab + kt * 32) : az;
#pragma unroll
            for (int n = 0; n < 8; ++n)
                acc[n] = __builtin_amdgcn_mfma_f32_16x16x32_bf16(a, b[n][kt], acc[n], 0, 0, 0);
        }

#pragma unroll
        for (int n = 0; n < 8; ++n)
            red[w][n][u] = acc[n];
        __syncthreads();

        float pre[4];
#pragma unroll
        for (int ga = 0; ga < 4; ++ga) {
            int n = ga * 2 + (chi >> 4);
            int sl = ((rho >> 2) << 4) + (chi & 15);
            int rg = rho & 3;
            const float* r0 = (const float*)&red[0][n][sl];
            const float* r1 = (const float*)&red[1][n][sl];
            const float* r2 = (const float*)&red[2][n][sl];
            const float* r3 = (const float*)&red[3][n][sl];
            pre[ga] = r0[rg] + r1[rg] + r2[rg] + r3[rg] + bf2f(xg[ga]);
        }
        float F = sigm(pre[0]);
        float I = sigm(pre[1]);
        float Cd = tanhf(pre[2]);
        float O = sigm(pre[3]);
        float cn = F * c + I * Cd;
        c = cn;
        float hf = tanhf(cn) * O;

        const size_t hidx = (size_t)(t * 64 + 8 * g + rho) * 1024 + 32 * i + chi;
        if (FAST) {
            // pair lanes (chi even | chi+1) into one 4B atomic swap -> lands dirty in XCD L2
            unsigned hv = (unsigned)f2bf(hf);
            unsigned nb = __shfl_down(hv, 1);
            if (!(chi & 1))
                at_swap32((unsigned*)&H[hidx], hv | (nb << 16));
        } else {
            __hip_atomic_store(&H[hidx], f2bf(hf), __ATOMIC_RELAXED, __HIP_MEMORY_SCOPE_AGENT);
        }
        if (t == 255) {
            out_h[(size_t)(8 * g + rho) * 1024 + 32 * i + chi] = hf;
            out_c[(size_t)(8 * g + rho) * 1024 + 32 * i + chi] = cn;
        }

        if (t < 255) {
            asm volatile("s_waitcnt vmcnt(0)" ::: "memory");  // h atomics done in L2
            __syncthreads();
            if (l == 0) {
                if (FAST)
                    at_swap32(&flags[g * 32 + i], (unsigned)(t + 1));  // L2 atomic flag
                else
                    __hip_atomic_store(&flags[g * 32 + i], (unsigned)(t + 1),
                                       __ATOMIC_RELAXED, __HIP_MEMORY_SCOPE_AGENT);
            }
            // per-wave poll: the 8 producers of this wave's K-slice (group WGs 8w..8w+7)
            const unsigned tgt = (unsigned)(t + 1);
            unsigned long long wd0 = __builtin_amdgcn_s_memrealtime();
            while (true) {
                unsigned f;
                if (FAST)
                    f = (u < 8) ? at_poll(&flags[g * 32 + 8 * w + u]) : tgt;  // L2 RMW read
                else
                    f = (u < 8) ? __hip_atomic_load(&flags[g * 32 + 8 * w + u],
                                                    __ATOMIC_RELAXED, __HIP_MEMORY_SCOPE_AGENT)
                                : tgt;
                if (__all(f >= tgt)) break;
                if (__builtin_amdgcn_s_memrealtime() - wd0 > WDOG_POLL) break;
                __builtin_amdgcn_s_sleep(2);
            }
            asm volatile("" ::: "memory");
            __builtin_amdgcn_sched_barrier(0);
            // next-step Xg prefetch AFTER poll: latency hides under next GEMM
#pragma unroll
            for (int ga = 0; ga < 4; ++ga)
                xg[ga] = Xg[(size_t)((t + 1) * 64 + 8 * g + rho) * 4096 + ga * 1024 + 32 * i + chi];
        }
    }
}

// ================= NOGO world: proven R5 64-WG scan (bids 0..63) =================
__device__ __forceinline__ void scan64(
    int bid, int l, int w, int u,
    const unsigned short* __restrict__ Whc, const unsigned short* __restrict__ Xg,
    const unsigned short* __restrict__ h0bf, unsigned short* __restrict__ H,
    const float* __restrict__ c0, float* __restrict__ out_h, float* __restrict__ out_c,
    unsigned int* __restrict__ flags, f32x4 (*red)[4][4][64], unsigned short* hs) {

    const int j0 = bid * 16;
    const int jj = u & 15, q = u >> 4;

    short8 b[4][8];
#pragma unroll
    for (int g = 0; g < 4; ++g)
#pragma unroll
        for (int kt = 0; kt < 8; ++kt)
            b[g][kt] = *(const short8*)&Whc[(size_t)(g * 1024 + j0 + jj) * 1024 + w * 256 + kt * 32 + q * 8];

    float c[4];
#pragma unroll
    for (int r = 0; r < 4; ++r)
        c[r] = c0[(size_t)(w * 16 + q * 4 + r) * 1024 + j0 + jj];

    unsigned short xg[4][4];
#pragma unroll
    for (int g = 0; g < 4; ++g)
#pragma unroll
        for (int r = 0; r < 4; ++r)
            xg[g][r] = Xg[(size_t)(w * 16 + q * 4 + r) * 4096 + g * 1024 + j0 + jj];

    const int srow_ = l >> 2, sqtr = l & 3;

#pragma unroll 1
    for (int t = 0; t < 256; ++t) {
        const unsigned short* hp = t ? (H + (size_t)(t - 1) * 65536) : h0bf;

        f32x4 acc[4][4] = {};
#pragma unroll
        for (int kt = 0; kt < 8; ++kt) {
            short8 a[4];
#pragma unroll
            for (int m = 0; m < 4; ++m)
                a[m] = *(const short8*)&hp[(size_t)(m * 16 + jj) * 1024 + w * 256 + kt * 32 + q * 8];
#pragma unroll
            for (int m = 0; m < 4; ++m)
#pragma unroll
                for (int g = 0; g < 4; ++g)
                    acc[m][g] = __builtin_amdgcn_mfma_f32_16x16x32_bf16(a[m], b[g][kt], acc[m][g], 0, 0, 0);
        }

        __syncthreads();
#pragma unroll
        for (int m = 0; m < 4; ++m)
#pragma unroll
            for (int g = 0; g < 4; ++g)
                red[m][w][g][u] = acc[m][g];
        __syncthreads();
        f32x4 gate[4];
#pragma unroll
        for (int g = 0; g < 4; ++g) {
            gate[g] = red[w][0][g][u];
#pragma unroll
            for (int w2 = 1; w2 < 4; ++w2)
                gate[g] += red[w][w2][g][u];
        }

#pragma unroll
        for (int r = 0; r < 4; ++r) {
            float F = sigm(gate[0][r] + bf2f(xg[0][r]));
            float I = sigm(gate[1][r] + bf2f(xg[1][r]));
            float Cd = tanhf(gate[2][r] + bf2f(xg[2][r]));
            float O = sigm(gate[3][r] + bf2f(xg[3][r]));
            float cn = F * c[r] + I * Cd;
            c[r] = cn;
            float hf = tanhf(cn) * O;
            int row = w * 16 + q * 4 + r;
            hs[row * 16 + jj] = f2bf(hf);
            if (t == 255) {
                out_h[(size_t)row * 1024 + j0 + jj] = hf;
                out_c[(size_t)row * 1024 + j0 + jj] = cn;
            }
        }
        __syncthreads();

        {
            unsigned long long v = *(const unsigned long long*)&hs[srow_ * 16 + sqtr * 4];
            __hip_atomic_store((unsigned long long*)&H[(size_t)(t * 64 + srow_) * 1024 + j0 + sqtr * 4],
                               v, __ATOMIC_RELAXED, __HIP_MEMORY_SCOPE_AGENT);
        }

        if (t < 255) {
            asm volatile("s_waitcnt vmcnt(0)" ::: "memory");
            __syncthreads();
            if (l == 0)
                __hip_atomic_store(&flags[bid], (unsigned)(t + 1),
                                   __ATOMIC_RELAXED, __HIP_MEMORY_SCOPE_AGENT);
#pragma unroll
            for (int g = 0; g < 4; ++g)
#pragma unroll
                for (int r = 0; r < 4; ++r)
                    xg[g][r] = Xg[(size_t)((t + 1) * 64 + w * 16 + q * 4 + r) * 4096 + g * 1024 + j0 + jj];
            const unsigned tgt = (unsigned)(t + 1);
            unsigned long long wd0 = __builtin_amdgcn_s_memrealtime();
            while (true) {
                unsigned f = __hip_atomic_load(&flags[16 * w + jj], __ATOMIC_RELAXED,
                                               __HIP_MEMORY_SCOPE_AGENT);
                if (__all(f >= tgt)) break;
                if (__builtin_amdgcn_s_memrealtime() - wd0 > WDOG_POLL) break;
                __builtin_amdgcn_s_sleep(4);
            }
            asm volatile("" ::: "memory");
            __builtin_amdgcn_sched_barrier(0);
        }
    }
}

// ================= dispatcher kernel =================
__global__ __launch_bounds__(256, 1) void lstm_scan(
    const unsigned short* __restrict__ Whc, const unsigned short* __restrict__ Xg,
    const unsigned short* __restrict__ h0bf, unsigned short* __restrict__ H,
    const float* __restrict__ c0, float* __restrict__ out_h, float* __restrict__ out_c,
    unsigned int* __restrict__ flags) {
    __shared__ __align__(16) char smem_[67584];   // GO: red[4][8][64] 32KB | NOGO: 64KB + hs 2KB
    __shared__ int s_dec;
    __shared__ int s_allsame;
    const int l = threadIdx.x, w = l >> 6, u = l & 63;
    const int bid = blockIdx.x;

    // ---- residency vote: arrive, decide (bid 0), read decision ----
    if (l == 0) {
        __hip_atomic_fetch_add(&flags[512], 1u, __ATOMIC_RELAXED, __HIP_MEMORY_SCOPE_AGENT);
        unsigned dec = 0;
        if (bid == 0) {
            unsigned long long t0 = __builtin_amdgcn_s_memrealtime();
            while (true) {
                unsigned cnt = __hip_atomic_load(&flags[512], __ATOMIC_RELAXED,
                                                 __HIP_MEMORY_SCOPE_AGENT);
                if (cnt >= 256u) { dec = 1u; break; }
                if (__builtin_amdgcn_s_memrealtime() - t0 > DEC_WAIT) { dec = 2u; break; }
                __builtin_amdgcn_s_sleep(8);
            }
            __hip_atomic_store(&flags[513], dec, __ATOMIC_RELAXED, __HIP_MEMORY_SCOPE_AGENT);
        } else {
            unsigned long long t0 = __builtin_amdgcn_s_memrealtime();
            while (true) {
                dec = __hip_atomic_load(&flags[513], __ATOMIC_RELAXED, __HIP_MEMORY_SCOPE_AGENT);
                if (dec) break;
                if (__builtin_amdgcn_s_memrealtime() - t0 > WDOG_DEC) { dec = 2u; break; }
                __builtin_amdgcn_s_sleep(8);
            }
        }
        s_dec = (int)dec;
    }
    __syncthreads();

    if (s_dec == 1) {
        // ---- GO: all 256 WGs resident. Per-group XCD homogeneity check ----
        const int g = bid & 7, i = bid >> 3;
        unsigned int* xcc = flags + 256;
        unsigned my_xcc;
        asm volatile("s_getreg_b32 %0, hwreg(HW_REG_XCC_ID)" : "=s"(my_xcc));
        if (l == 0)
            __hip_atomic_store(&xcc[bid], 256u | (my_xcc & 255u),
                               __ATOMIC_RELAXED, __HIP_MEMORY_SCOPE_AGENT);
        if (w == 0) {
            unsigned v = 256u;
            unsigned long long wd0 = __builtin_amdgcn_s_memrealtime();
            int timeout = 0;
            while (true) {
                v = (u < 32) ? __hip_atomic_load(&xcc[(u << 3) | g], __ATOMIC_RELAXED,
                                                 __HIP_MEMORY_SCOPE_AGENT)
                             : 257u;
                unsigned long long rdy = __ballot(v >= 256u);
                if (rdy == ~0ull) break;
                if (__builtin_amdgcn_s_memrealtime() - wd0 > WDOG_DEC) { timeout = 1; break; }
                __builtin_amdgcn_s_sleep(8);
            }
            unsigned first = __shfl(v, 0);
            int same = ((u < 32) ? (v == first) : 1) ? 1 : 0;
            unsigned long long m = __ballot(same);
            if (u == 0) s_allsame = (!timeout && m == ~0ull) ? 1 : 0;
        }
        __syncthreads();

        f32x4 (*red)[8][64] = (f32x4(*)[8][64])smem_;
        if (s_allsame)
            scan_go<1>(g, i, l, w, u, Whc, Xg, h0bf, H, c0, out_h, out_c, flags, red);
        else
            scan_go<0>(g, i, l, w, u, Whc, Xg, h0bf, H, c0, out_h, out_c, flags, red);
    } else {
        // ---- NOGO: bids >= 64 exit (frees CUs); bids < 64 run proven R5 scan ----
        if (bid >= 64) return;
        f32x4 (*red64)[4][4][64] = (f32x4(*)[4][4][64])smem_;
        unsigned short* hs = (unsigned short*)(smem_ + 65536);
        scan64(bid, l, w, u, Whc, Xg, h0bf, H, c0, out_h, out_c, flags, red64, hs);
    }
}

// ---------- launch ----------
extern "C" void kernel_launch(void* const* d_in, const int* in_sizes, int n_in,
                              void* d_out, int out_size, void* d_ws, size_t ws_size,
                              hipStream_t stream) {
    const float* steps = (const float*)d_in[0];
    const float* h0 = (const float*)d_in[1];
    const float* c0 = (const float*)d_in[2];
    const float* Wfx = (const float*)d_in[3];
    const float* Wfh = (const float*)d_in[4];
    const float* bf_ = (const float*)d_in[5];
    const float* Wix = (const float*)d_in[6];
    const float* Wih = (const float*)d_in[7];
    const float* bi_ = (const float*)d_in[8];
    const float* Wcx = (const float*)d_in[9];
    const float* Wch = (const float*)d_in[10];
    const float* bc_ = (const float*)d_in[11];
    const float* Wox = (const float*)d_in[12];
    const float* Woh = (const float*)d_in[13];
    const float* bo_ = (const float*)d_in[14];
    const float* Wy = (const float*)d_in[15];
    const float* by_ = (const float*)d_in[16];

    char* ws = (char*)d_ws;
    unsigned short* Xbf = (unsigned short*)(ws + 0L);           //  33,554,432 B
    unsigned short* Xg  = (unsigned short*)(ws + 33554432L);    // 134,217,728 B
    unsigned short* H   = (unsigned short*)(ws + 167772160L);   //  33,554,432 B
    unsigned short* Wx  = (unsigned short*)(ws + 201326592L);   //   8,388,608 B
    unsigned short* Wh  = (unsigned short*)(ws + 209715200L);   //   8,388,608 B
    unsigned short* Wyt = (unsigned short*)(ws + 218103808L);   //   2,097,152 B
    float* bcat         = (float*)(ws + 220200960L);            //      16,384 B
    unsigned short* hbuf0 = (unsigned short*)(ws + 220217344L); //     131,072 B
    unsigned int* flags = (unsigned int*)(ws + 220348416L);     //       4,096 B

    float* out_y = (float*)d_out;
    float* out_h = out_y + 16777216L;
    float* out_c = out_h + 65536L;

    // 1. convert X to bf16
    conv_bf16<<<2048, 256, 0, stream>>>((const float4*)steps, (ushort4*)Xbf, 4194304);

    // 2. transpose-pack all weights to bf16 [N][K]
    PackArgs pa;
    pa.src[0] = Wfx; pa.src[1] = Wix; pa.src[2] = Wcx; pa.src[3] = Wox;
    pa.src[4] = Wfh; pa.src[5] = Wih; pa.src[6] = Wch; pa.src[7] = Woh;
    pa.src[8] = Wy;
    pack_w<<<dim3(32, 32, 9), 256, 0, stream>>>(pa, Wx, Wh, Wyt);

    // 3. small init (h0->bf16, bias concat, flags = 0) — runs every replay
    init_small<<<256, 256, 0, stream>>>(h0, bf_, bi_, bc_, bo_, hbuf0, bcat, flags);

    // 4. Xg = X @ Wxcat + bcat   (M=16384, N=4096, K=1024), bf16 out
    gemm_bt<1><<<dim3(32, 128), 256, 0, stream>>>(Xbf, Wx, bcat, Xg, 16384, 4096, 1024);

    // 5. persistent scan: plain 256-WG launch, residency vote, XCD-local FAST path
    lstm_scan<<<256, 256, 0, stream>>>(Wh, Xg, hbuf0, H, c0, out_h, out_c, flags);

    // 6. Y = H @ Wy + by  (M=16384, N=1024, K=1024), fp32 out to d_out
    gemm_bt<0><<<dim3(8, 128), 256, 0, stream>>>(H, Wyt, by_, (void*)d_out, 16384, 1024, 1024);
}

// Round 12
// 1402.497 us; speedup vs baseline: 3427.3398x; 1.3962x over previous
//
#include <hip/hip_runtime.h>

// ---------- types / helpers ----------
typedef short short8 __attribute__((ext_vector_type(8)));
typedef float f32x4 __attribute__((ext_vector_type(4)));

__device__ __forceinline__ float bf2f(unsigned short s) {
    unsigned int u = ((unsigned int)s) << 16;
    return __builtin_bit_cast(float, u);
}
__device__ __forceinline__ unsigned short f2bf(float f) {
    unsigned int u = __builtin_bit_cast(unsigned int, f);
    u += 0x7fffu + ((u >> 16) & 1u);
    return (unsigned short)(u >> 16);
}
__device__ __forceinline__ float sigm(float x) { return 1.0f / (1.0f + __expf(-x)); }

__device__ __forceinline__ void gload16(const void* g, void* l) {
    __builtin_amdgcn_global_load_lds((const __attribute__((address_space(1))) void*)g,
                                     (__attribute__((address_space(3))) void*)l, 16, 0, 0);
}

// No-sc global atomics execute at the local XCD L2 and bypass L1 on both sides
// (proven R11: only reliable XCD-local producer->consumer primitive on gfx950).
__device__ __forceinline__ void at_swap64(unsigned long long* p, unsigned long long v) {
    asm volatile("global_atomic_swap_x2 %0, %1, off" :: "v"(p), "v"(v) : "memory");
}
__device__ __forceinline__ void at_add_nr(unsigned* p, unsigned v) {
    asm volatile("global_atomic_add %0, %1, off" :: "v"(p), "v"(v) : "memory");
}
__device__ __forceinline__ unsigned at_poll(unsigned* p) {
    unsigned v;
    asm volatile("global_atomic_add %0, %1, %2, off sc0\n\ts_waitcnt vmcnt(0)"
                 : "=v"(v) : "v"(p), "v"(0u) : "memory");
    return v;
}

#define WDOG_POLL 200000ull    // 2 ms — never fires when healthy; bug -> slow-but-correct
#define WDOG_DEC  2000000ull   // 20 ms
#define DEC_WAIT  10000ull     // 100 us decider patience

// ---------- kernel: fp32 -> bf16 vectorized convert ----------
__global__ void conv_bf16(const float4* __restrict__ src, ushort4* __restrict__ dst, int n4) {
    for (int i = blockIdx.x * blockDim.x + threadIdx.x; i < n4; i += gridDim.x * blockDim.x) {
        float4 v = src[i];
        ushort4 o;
        o.x = f2bf(v.x); o.y = f2bf(v.y); o.z = f2bf(v.z); o.w = f2bf(v.w);
        dst[i] = o;
    }
}

// ---------- kernel: transpose+convert 9 weight matrices to bf16 [N][K] ----------
struct PackArgs { const float* src[9]; };

__global__ __launch_bounds__(256) void pack_w(PackArgs pa,
                                              unsigned short* __restrict__ Wx,
                                              unsigned short* __restrict__ Wh,
                                              unsigned short* __restrict__ Wyt) {
    __shared__ float tile[32][33];
    const int z = blockIdx.z;
    const float* S = pa.src[z];
    unsigned short* D = (z < 4) ? Wx + (long)z * 1048576
                                : (z < 8) ? Wh + (long)(z - 4) * 1048576
                                          : Wyt;
    const int tx = threadIdx.x & 31, ty = threadIdx.x >> 5;
    const int rb = blockIdx.y * 32, cb = blockIdx.x * 32;
#pragma unroll
    for (int rr = 0; rr < 4; ++rr) {
        int r = ty + rr * 8;
        tile[r][tx] = S[(long)(rb + r) * 1024 + cb + tx];
    }
    __syncthreads();
#pragma unroll
    for (int rr = 0; rr < 4; ++rr) {
        int r = ty + rr * 8;
        D[(long)(cb + r) * 1024 + rb + tx] = f2bf(tile[tx][r]);
    }
}

// ---------- kernel: small init (bias concat, h0->bf16, flags=0) ----------
__global__ void init_small(const float* __restrict__ h0,
                           const float* __restrict__ bf_, const float* __restrict__ bi_,
                           const float* __restrict__ bc_, const float* __restrict__ bo_,
                           unsigned short* __restrict__ hbuf0,
                           float* __restrict__ bcat, unsigned int* __restrict__ flags) {
    int i = blockIdx.x * blockDim.x + threadIdx.x;
    if (i < 1024) flags[i] = 0u;   // gctr[g*16] | slow flags[0..256) | xcc[256..512) | arrive[512] | dec[513]
    if (i < 65536) hbuf0[i] = f2bf(h0[i]);
    if (i < 4096) {
        const float* bs = (i < 1024) ? bf_ : (i < 2048) ? bi_ : (i < 3072) ? bc_ : bo_;
        bcat[i] = bs[i & 1023];
    }
}

// ---------- kernel: 128x128 bf16 MFMA GEMM, A[M][K] x B^T[N][K] + bias ----------
template <int OUT_BF16>
__global__ __launch_bounds__(256) void gemm_bt(const unsigned short* __restrict__ A,
                                               const unsigned short* __restrict__ B,
                                               const float* __restrict__ bias,
                                               void* __restrict__ Cout,
                                               int M, int N, int K) {
    __shared__ unsigned short As[128 * 32];
    __shared__ unsigned short Bs[128 * 32];
    const int l = threadIdx.x;
    const int w = l >> 6, u = l & 63;
    const int wr = w >> 1, wc = w & 1;
    const long rowbase = (long)blockIdx.y * 128;
    const long colbase = (long)blockIdx.x * 128;

    f32x4 acc[4][4] = {};

    const int srow = l >> 2;
    const int sunit = l & 3;

    for (int k0 = 0; k0 < K; k0 += 32) {
#pragma unroll
        for (int i = 0; i < 2; ++i) {
            int row = i * 64 + srow;
            int su = sunit ^ (row & 3);
            gload16(&A[(rowbase + row) * K + k0 + su * 8], &As[i * 2048 + l * 8]);
            gload16(&B[(colbase + row) * K + k0 + su * 8], &Bs[i * 2048 + l * 8]);
        }
        __syncthreads();
        short8 a[4], b[4];
#pragma unroll
        for (int mi = 0; mi < 4; ++mi) {
            int row = wr * 64 + mi * 16 + (u & 15);
            a[mi] = *(const short8*)&As[row * 32 + (((u >> 4) ^ (row & 3))) * 8];
        }
#pragma unroll
        for (int ni = 0; ni < 4; ++ni) {
            int row = wc * 64 + ni * 16 + (u & 15);
            b[ni] = *(const short8*)&Bs[row * 32 + (((u >> 4) ^ (row & 3))) * 8];
        }
#pragma unroll
        for (int mi = 0; mi < 4; ++mi)
#pragma unroll
            for (int ni = 0; ni < 4; ++ni)
                acc[mi][ni] = __builtin_amdgcn_mfma_f32_16x16x32_bf16(a[mi], b[ni], acc[mi][ni], 0, 0, 0);
        __syncthreads();
    }

#pragma unroll
    for (int mi = 0; mi < 4; ++mi) {
#pragma unroll
        for (int ni = 0; ni < 4; ++ni) {
#pragma unroll
            for (int r = 0; r < 4; ++r) {
                long row = rowbase + wr * 64 + mi * 16 + (u >> 4) * 4 + r;
                long col = colbase + wc * 64 + ni * 16 + (u & 15);
                float v = acc[mi][ni][r] + bias[col];
                if (OUT_BF16)
                    ((unsigned short*)Cout)[row * N + col] = f2bf(v);
                else
                    ((float*)Cout)[row * N + col] = v;
            }
        }
    }
}

// ================= GO world: batch-partitioned XCD-local scan (256 WGs) =================
// Group g = {bid: bid%8==g} (32 WGs, one XCD) owns batch rows [8g,8g+8). WG i=bid>>3 owns
// hidden cols [32i,32i+32). Wave w = K-slice [256w,..+256). Weights in VGPRs; c in regs.
// FAST sync (R12): h publish via 8B atomic swaps; ONE group-epoch atomic counter
// (+1/WG/step); ONE poller per WG (thread 0) + syncthreads release. Cuts the R11
// poll-RMW contention (1024 pollers/XCD on 2 lines -> 32 pollers on 1 line, 8x slower rate).
template <int FAST>
__device__ __forceinline__ void scan_go(
    int g, int i, int l, int w, int u,
    const unsigned short* __restrict__ Whc, const unsigned short* __restrict__ Xg,
    const unsigned short* __restrict__ h0bf, unsigned short* __restrict__ H,
    const float* __restrict__ c0, float* __restrict__ out_h, float* __restrict__ out_c,
    unsigned int* __restrict__ flags, f32x4 (*red)[8][64]) {

    const int rho = l >> 5, chi = l & 31;
    const int arow = u & 15;
    const int kofs = (u >> 4) * 8;

    short8 b[8][8];
#pragma unroll
    for (int n = 0; n < 8; ++n)
#pragma unroll
        for (int kt = 0; kt < 8; ++kt)
            b[n][kt] = *(const short8*)&Whc[(size_t)((n >> 1) * 1024 + 32 * i + 16 * (n & 1) + arow) * 1024
                                            + w * 256 + kt * 32 + kofs];

    float c = c0[(size_t)(8 * g + rho) * 1024 + 32 * i + chi];

    unsigned short xg[4];
#pragma unroll
    for (int ga = 0; ga < 4; ++ga)
        xg[ga] = Xg[(size_t)(8 * g + rho) * 4096 + ga * 1024 + 32 * i + chi];

    const short8 az = {};
    unsigned int* gctr = &flags[g * 16];   // per-group epoch counter, own 64B line

#pragma unroll 1
    for (int t = 0; t < 256; ++t) {
        const unsigned short* hp = t ? (H + (size_t)(t - 1) * 65536 + 8 * g * 1024)
                                     : (h0bf + 8 * g * 1024);
        const unsigned short* ab = hp + (size_t)arow * 1024 + w * 256 + kofs;

        f32x4 acc[8] = {};
#pragma unroll
        for (int kt = 0; kt < 8; ++kt) {
            short8 a = (arow < 8) ? *(const short8*)(ab + kt * 32) : az;
#pragma unroll
            for (int n = 0; n < 8; ++n)
                acc[n] = __builtin_amdgcn_mfma_f32_16x16x32_bf16(a, b[n][kt], acc[n], 0, 0, 0);
        }

#pragma unroll
        for (int n = 0; n < 8; ++n)
            red[w][n][u] = acc[n];
        __syncthreads();

        float pre[4];
#pragma unroll
        for (int ga = 0; ga < 4; ++ga) {
            int n = ga * 2 + (chi >> 4);
            int sl = ((rho >> 2) << 4) + (chi & 15);
            int rg = rho & 3;
            const float* r0 = (const float*)&red[0][n][sl];
            const float* r1 = (const float*)&red[1][n][sl];
            const float* r2 = (const float*)&red[2][n][sl];
            const float* r3 = (const float*)&red[3][n][sl];
            pre[ga] = r0[rg] + r1[rg] + r2[rg] + r3[rg] + bf2f(xg[ga]);
        }
        float F = sigm(pre[0]);
        float I = sigm(pre[1]);
        float Cd = tanhf(pre[2]);
        float O = sigm(pre[3]);
        float cn = F * c + I * Cd;
        c = cn;
        float hf = tanhf(cn) * O;

        const size_t hidx = (size_t)(t * 64 + 8 * g + rho) * 1024 + 32 * i + chi;
        if (FAST) {
            // pack 4 lanes (chi..chi+3, same rho) into one 8B atomic swap -> XCD L2
            unsigned hv = (unsigned)f2bf(hf);
            unsigned p01 = hv | (__shfl_down(hv, 1) << 16);
            unsigned p23 = __shfl_down(p01, 2);
            if (!(chi & 3)) {
                unsigned long long v64 = (unsigned long long)p01 |
                                         ((unsigned long long)p23 << 32);
                at_swap64((unsigned long long*)&H[hidx], v64);
            }
        } else {
            __hip_atomic_store(&H[hidx], f2bf(hf), __ATOMIC_RELAXED, __HIP_MEMORY_SCOPE_AGENT);
        }
        if (t == 255) {
            out_h[(size_t)(8 * g + rho) * 1024 + 32 * i + chi] = hf;
            out_c[(size_t)(8 * g + rho) * 1024 + 32 * i + chi] = cn;
        }

        if (t < 255) {
            asm volatile("s_waitcnt vmcnt(0)" ::: "memory");  // h atomics done in L2
            __syncthreads();
            if (l == 0) {
                if (FAST)
                    at_add_nr(gctr, 1u);   // epoch: counter == 32*(t+1) when group done
                else
                    __hip_atomic_store(&flags[32 + g * 32 + i], (unsigned)(t + 1),
                                       __ATOMIC_RELAXED, __HIP_MEMORY_SCOPE_AGENT);
            }
            // next-step Xg prefetch: HBM latency hides under the poll wait
#pragma unroll
            for (int ga = 0; ga < 4; ++ga)
                xg[ga] = Xg[(size_t)((t + 1) * 64 + 8 * g + rho) * 4096 + ga * 1024 + 32 * i + chi];

            if (FAST) {
                if (l == 0) {   // single poller per WG
                    const unsigned tgt = 32u * (unsigned)(t + 1);
                    unsigned long long wd0 = __builtin_amdgcn_s_memrealtime();
                    while (true) {
                        unsigned f = at_poll(gctr);
                        if (f >= tgt) break;
                        if (__builtin_amdgcn_s_memrealtime() - wd0 > WDOG_POLL) break;
                        __builtin_amdgcn_s_sleep(4);
                    }
                }
                __syncthreads();  // release whole WG
            } else {
                const unsigned tgt = (unsigned)(t + 1);
                unsigned long long wd0 = __builtin_amdgcn_s_memrealtime();
                while (true) {
                    unsigned f = (u < 8) ? __hip_atomic_load(&flags[32 + g * 32 + 8 * w + u],
                                                             __ATOMIC_RELAXED, __HIP_MEMORY_SCOPE_AGENT)
                                         : tgt;
                    if (__all(f >= tgt)) break;
                    if (__builtin_amdgcn_s_memrealtime() - wd0 > WDOG_POLL) break;
                    __builtin_amdgcn_s_sleep(2);
                }
            }
            asm volatile("" ::: "memory");
            __builtin_amdgcn_sched_barrier(0);
        }
    }
}

// ================= NOGO world: proven R5 64-WG scan (bids 0..63) =================
__device__ __forceinline__ void scan64(
    int bid, int l, int w, int u,
    const unsigned short* __restrict__ Whc, const unsigned short* __restrict__ Xg,
    const unsigned short* __restrict__ h0bf, unsigned short* __restrict__ H,
    const float* __restrict__ c0, float* __restrict__ out_h, float* __restrict__ out_c,
    unsigned int* __restrict__ flags, f32x4 (*red)[4][4][64], unsigned short* hs) {

    const int j0 = bid * 16;
    const int jj = u & 15, q = u >> 4;

    short8 b[4][8];
#pragma unroll
    for (int g = 0; g < 4; ++g)
#pragma unroll
        for (int kt = 0; kt < 8; ++kt)
            b[g][kt] = *(const short8*)&Whc[(size_t)(g * 1024 + j0 + jj) * 1024 + w * 256 + kt * 32 + q * 8];

    float c[4];
#pragma unroll
    for (int r = 0; r < 4; ++r)
        c[r] = c0[(size_t)(w * 16 + q * 4 + r) * 1024 + j0 + jj];

    unsigned short xg[4][4];
#pragma unroll
    for (int g = 0; g < 4; ++g)
#pragma unroll
        for (int r = 0; r < 4; ++r)
            xg[g][r] = Xg[(size_t)(w * 16 + q * 4 + r) * 4096 + g * 1024 + j0 + jj];

    const int srow_ = l >> 2, sqtr = l & 3;

#pragma unroll 1
    for (int t = 0; t < 256; ++t) {
        const unsigned short* hp = t ? (H + (size_t)(t - 1) * 65536) : h0bf;

        f32x4 acc[4][4] = {};
#pragma unroll
        for (int kt = 0; kt < 8; ++kt) {
            short8 a[4];
#pragma unroll
            for (int m = 0; m < 4; ++m)
                a[m] = *(const short8*)&hp[(size_t)(m * 16 + jj) * 1024 + w * 256 + kt * 32 + q * 8];
#pragma unroll
            for (int m = 0; m < 4; ++m)
#pragma unroll
                for (int g = 0; g < 4; ++g)
                    acc[m][g] = __builtin_amdgcn_mfma_f32_16x16x32_bf16(a[m], b[g][kt], acc[m][g], 0, 0, 0);
        }

        __syncthreads();
#pragma unroll
        for (int m = 0; m < 4; ++m)
#pragma unroll
            for (int g = 0; g < 4; ++g)
                red[m][w][g][u] = acc[m][g];
        __syncthreads();
        f32x4 gate[4];
#pragma unroll
        for (int g = 0; g < 4; ++g) {
            gate[g] = red[w][0][g][u];
#pragma unroll
            for (int w2 = 1; w2 < 4; ++w2)
                gate[g] += red[w][w2][g][u];
        }

#pragma unroll
        for (int r = 0; r < 4; ++r) {
            float F = sigm(gate[0][r] + bf2f(xg[0][r]));
            float I = sigm(gate[1][r] + bf2f(xg[1][r]));
            float Cd = tanhf(gate[2][r] + bf2f(xg[2][r]));
            float O = sigm(gate[3][r] + bf2f(xg[3][r]));
            float cn = F * c[r] + I * Cd;
            c[r] = cn;
            float hf = tanhf(cn) * O;
            int row = w * 16 + q * 4 + r;
            hs[row * 16 + jj] = f2bf(hf);
            if (t == 255) {
                out_h[(size_t)row * 1024 + j0 + jj] = hf;
                out_c[(size_t)row * 1024 + j0 + jj] = cn;
            }
        }
        __syncthreads();

        {
            unsigned long long v = *(const unsigned long long*)&hs[srow_ * 16 + sqtr * 4];
            __hip_atomic_store((unsigned long long*)&H[(size_t)(t * 64 + srow_) * 1024 + j0 + sqtr * 4],
                               v, __ATOMIC_RELAXED, __HIP_MEMORY_SCOPE_AGENT);
        }

        if (t < 255) {
            asm volatile("s_waitcnt vmcnt(0)" ::: "memory");
            __syncthreads();
            if (l == 0)
                __hip_atomic_store(&flags[512 + bid], (unsigned)(t + 1),
                                   __ATOMIC_RELAXED, __HIP_MEMORY_SCOPE_AGENT);
#pragma unroll
            for (int g = 0; g < 4; ++g)
#pragma unroll
                for (int r = 0; r < 4; ++r)
                    xg[g][r] = Xg[(size_t)((t + 1) * 64 + w * 16 + q * 4 + r) * 4096 + g * 1024 + j0 + jj];
            const unsigned tgt = (unsigned)(t + 1);
            unsigned long long wd0 = __builtin_amdgcn_s_memrealtime();
            while (true) {
                unsigned f = __hip_atomic_load(&flags[512 + 16 * w + jj], __ATOMIC_RELAXED,
                                               __HIP_MEMORY_SCOPE_AGENT);
                if (__all(f >= tgt)) break;
                if (__builtin_amdgcn_s_memrealtime() - wd0 > WDOG_POLL) break;
                __builtin_amdgcn_s_sleep(4);
            }
            asm volatile("" ::: "memory");
            __builtin_amdgcn_sched_barrier(0);
        }
    }
}

// ================= dispatcher kernel =================
// flags layout: [0..128) gctr per group (g*16, 64B apart) | [32+g*32+i] SLOW flags
// (overlaps gctr region harmlessly: FAST and SLOW are mutually exclusive per run)
// | [256..512) xcc | [512..576) scan64 flags | [576] arrive | [577] dec
__global__ __launch_bounds__(256, 1) void lstm_scan(
    const unsigned short* __restrict__ Whc, const unsigned short* __restrict__ Xg,
    const unsigned short* __restrict__ h0bf, unsigned short* __restrict__ H,
    const float* __restrict__ c0, float* __restrict__ out_h, float* __restrict__ out_c,
    unsigned int* __restrict__ flags) {
    __shared__ __align__(16) char smem_[67584];   // GO: red[4][8][64] 32KB | NOGO: 64KB + hs 2KB
    __shared__ int s_dec;
    __shared__ int s_allsame;
    const int l = threadIdx.x, w = l >> 6, u = l & 63;
    const int bid = blockIdx.x;

    // ---- residency vote: arrive, decide (bid 0), read decision ----
    if (l == 0) {
        __hip_atomic_fetch_add(&flags[576], 1u, __ATOMIC_RELAXED, __HIP_MEMORY_SCOPE_AGENT);
        unsigned dec = 0;
        if (bid == 0) {
            unsigned long long t0 = __builtin_amdgcn_s_memrealtime();
            while (true) {
                unsigned cnt = __hip_atomic_load(&flags[576], __ATOMIC_RELAXED,
                                                 __HIP_MEMORY_SCOPE_AGENT);
                if (cnt >= 256u) { dec = 1u; break; }
                if (__builtin_amdgcn_s_memrealtime() - t0 > DEC_WAIT) { dec = 2u; break; }
                __builtin_amdgcn_s_sleep(8);
            }
            __hip_atomic_store(&flags[577], dec, __ATOMIC_RELAXED, __HIP_MEMORY_SCOPE_AGENT);
        } else {
            unsigned long long t0 = __builtin_amdgcn_s_memrealtime();
            while (true) {
                dec = __hip_atomic_load(&flags[577], __ATOMIC_RELAXED, __HIP_MEMORY_SCOPE_AGENT);
                if (dec) break;
                if (__builtin_amdgcn_s_memrealtime() - t0 > WDOG_DEC) { dec = 2u; break; }
                __builtin_amdgcn_s_sleep(8);
            }
        }
        s_dec = (int)dec;
    }
    __syncthreads();

    if (s_dec == 1) {
        // ---- GO: all 256 WGs resident. Per-group XCD homogeneity check ----
        const int g = bid & 7, i = bid >> 3;
        unsigned int* xcc = flags + 256;
        unsigned my_xcc;
        asm volatile("s_getreg_b32 %0, hwreg(HW_REG_XCC_ID)" : "=s"(my_xcc));
        if (l == 0)
            __hip_atomic_store(&xcc[bid], 256u | (my_xcc & 255u),
                               __ATOMIC_RELAXED, __HIP_MEMORY_SCOPE_AGENT);
        if (w == 0) {
            unsigned v = 256u;
            unsigned long long wd0 = __builtin_amdgcn_s_memrealtime();
            int timeout = 0;
            while (true) {
                v = (u < 32) ? __hip_atomic_load(&xcc[(u << 3) | g], __ATOMIC_RELAXED,
                                                 __HIP_MEMORY_SCOPE_AGENT)
                             : 257u;
                unsigned long long rdy = __ballot(v >= 256u);
                if (rdy == ~0ull) break;
                if (__builtin_amdgcn_s_memrealtime() - wd0 > WDOG_DEC) { timeout = 1; break; }
                __builtin_amdgcn_s_sleep(8);
            }
            unsigned first = __shfl(v, 0);
            int same = ((u < 32) ? (v == first) : 1) ? 1 : 0;
            unsigned long long m = __ballot(same);
            if (u == 0) s_allsame = (!timeout && m == ~0ull) ? 1 : 0;
        }
        __syncthreads();

        f32x4 (*red)[8][64] = (f32x4(*)[8][64])smem_;
        if (s_allsame)
            scan_go<1>(g, i, l, w, u, Whc, Xg, h0bf, H, c0, out_h, out_c, flags, red);
        else
            scan_go<0>(g, i, l, w, u, Whc, Xg, h0bf, H, c0, out_h, out_c, flags, red);
    } else {
        // ---- NOGO: bids >= 64 exit (frees CUs); bids < 64 run proven R5 scan ----
        if (bid >= 64) return;
        f32x4 (*red64)[4][4][64] = (f32x4(*)[4][4][64])smem_;
        unsigned short* hs = (unsigned short*)(smem_ + 65536);
        scan64(bid, l, w, u, Whc, Xg, h0bf, H, c0, out_h, out_c, flags, red64, hs);
    }
}

// ---------- launch ----------
extern "C" void kernel_launch(void* const* d_in, const int* in_sizes, int n_in,
                              void* d_out, int out_size, void* d_ws, size_t ws_size,
                              hipStream_t stream) {
    const float* steps = (const float*)d_in[0];
    const float* h0 = (const float*)d_in[1];
    const float* c0 = (const float*)d_in[2];
    const float* Wfx = (const float*)d_in[3];
    const float* Wfh = (const float*)d_in[4];
    const float* bf_ = (const float*)d_in[5];
    const float* Wix = (const float*)d_in[6];
    const float* Wih = (const float*)d_in[7];
    const float* bi_ = (const float*)d_in[8];
    const float* Wcx = (const float*)d_in[9];
    const float* Wch = (const float*)d_in[10];
    const float* bc_ = (const float*)d_in[11];
    const float* Wox = (const float*)d_in[12];
    const float* Woh = (const float*)d_in[13];
    const float* bo_ = (const float*)d_in[14];
    const float* Wy = (const float*)d_in[15];
    const float* by_ = (const float*)d_in[16];

    char* ws = (char*)d_ws;
    unsigned short* Xbf = (unsigned short*)(ws + 0L);           //  33,554,432 B
    unsigned short* Xg  = (unsigned short*)(ws + 33554432L);    // 134,217,728 B
    unsigned short* H   = (unsigned short*)(ws + 167772160L);   //  33,554,432 B
    unsigned short* Wx  = (unsigned short*)(ws + 201326592L);   //   8,388,608 B
    unsigned short* Wh  = (unsigned short*)(ws + 209715200L);   //   8,388,608 B
    unsigned short* Wyt = (unsigned short*)(ws + 218103808L);   //   2,097,152 B
    float* bcat         = (float*)(ws + 220200960L);            //      16,384 B
    unsigned short* hbuf0 = (unsigned short*)(ws + 220217344L); //     131,072 B
    unsigned int* flags = (unsigned int*)(ws + 220348416L);     //       4,096 B

    float* out_y = (float*)d_out;
    float* out_h = out_y + 16777216L;
    float* out_c = out_h + 65536L;

    // 1. convert X to bf16
    conv_bf16<<<2048, 256, 0, stream>>>((const float4*)steps, (ushort4*)Xbf, 4194304);

    // 2. transpose-pack all weights to bf16 [N][K]
    PackArgs pa;
    pa.src[0] = Wfx; pa.src[1] = Wix; pa.src[2] = Wcx; pa.src[3] = Wox;
    pa.src[4] = Wfh; pa.src[5] = Wih; pa.src[6] = Wch; pa.src[7] = Woh;
    pa.src[8] = Wy;
    pack_w<<<dim3(32, 32, 9), 256, 0, stream>>>(pa, Wx, Wh, Wyt);

    // 3. small init (h0->bf16, bias concat, flags = 0) — runs every replay
    init_small<<<256, 256, 0, stream>>>(h0, bf_, bi_, bc_, bo_, hbuf0, bcat, flags);

    // 4. Xg = X @ Wxcat + bcat   (M=16384, N=4096, K=1024), bf16 out
    gemm_bt<1><<<dim3(32, 128), 256, 0, stream>>>(Xbf, Wx, bcat, Xg, 16384, 4096, 1024);

    // 5. persistent scan: plain 256-WG launch, residency vote, XCD-local FAST path
    lstm_scan<<<256, 256, 0, stream>>>(Wh, Xg, hbuf0, H, c0, out_h, out_c, flags);

    // 6. Y = H @ Wy + by  (M=16384, N=1024, K=1024), fp32 out to d_out
    gemm_bt<0><<<dim3(8, 128), 256, 0, stream>>>(H, Wyt, by_, (void*)d_out, 16384, 1024, 1024);
}

// Round 13
// 1310.591 us; speedup vs baseline: 3667.6860x; 1.0701x over previous
//
#include <hip/hip_runtime.h>

// ---------- types / helpers ----------
typedef short short8 __attribute__((ext_vector_type(8)));
typedef float f32x4 __attribute__((ext_vector_type(4)));

__device__ __forceinline__ float bf2f(unsigned short s) {
    unsigned int u = ((unsigned int)s) << 16;
    return __builtin_bit_cast(float, u);
}
__device__ __forceinline__ unsigned short f2bf(float f) {
    unsigned int u = __builtin_bit_cast(unsigned int, f);
    u += 0x7fffu + ((u >> 16) & 1u);
    return (unsigned short)(u >> 16);
}
__device__ __forceinline__ float sigm(float x) { return 1.0f / (1.0f + __expf(-x)); }

__device__ __forceinline__ void gload16(const void* g, void* l) {
    __builtin_amdgcn_global_load_lds((const __attribute__((address_space(1))) void*)g,
                                     (__attribute__((address_space(3))) void*)l, 16, 0, 0);
}

// No-sc global atomics execute at the local XCD L2 and bypass L1 on both sides
// (proven R11/R12: the reliable XCD-local producer->consumer primitive on gfx950).
__device__ __forceinline__ void at_swap64(unsigned long long* p, unsigned long long v) {
    asm volatile("global_atomic_swap_x2 %0, %1, off" :: "v"(p), "v"(v) : "memory");
}
__device__ __forceinline__ void at_add_nr(unsigned* p, unsigned v) {
    asm volatile("global_atomic_add %0, %1, off" :: "v"(p), "v"(v) : "memory");
}
__device__ __forceinline__ unsigned at_poll(unsigned* p) {
    unsigned v;
    asm volatile("global_atomic_add %0, %1, %2, off sc0\n\ts_waitcnt vmcnt(0)"
                 : "=v"(v) : "v"(p), "v"(0u) : "memory");
    return v;
}

#define WDOG_POLL 200000ull    // 2 ms — never fires when healthy; bug -> slow-but-correct
#define WDOG_DEC  2000000ull   // 20 ms
#define DEC_WAIT  10000ull     // 100 us decider patience

// flags layout (uints): [256..512) xcc | [512..576) scan64 flags | [576] arrive
// [577] dec | [640+g*16] FAST group epoch ctr | [768+g*32+i] SLOW flags. All < 1024.

// ---------- kernel: fp32 -> bf16 vectorized convert ----------
__global__ void conv_bf16(const float4* __restrict__ src, ushort4* __restrict__ dst, int n4) {
    for (int i = blockIdx.x * blockDim.x + threadIdx.x; i < n4; i += gridDim.x * blockDim.x) {
        float4 v = src[i];
        ushort4 o;
        o.x = f2bf(v.x); o.y = f2bf(v.y); o.z = f2bf(v.z); o.w = f2bf(v.w);
        dst[i] = o;
    }
}

// ---------- kernel: transpose+convert 9 weight matrices to bf16 [N][K] ----------
struct PackArgs { const float* src[9]; };

__global__ __launch_bounds__(256) void pack_w(PackArgs pa,
                                              unsigned short* __restrict__ Wx,
                                              unsigned short* __restrict__ Wh,
                                              unsigned short* __restrict__ Wyt) {
    __shared__ float tile[32][33];
    const int z = blockIdx.z;
    const float* S = pa.src[z];
    unsigned short* D = (z < 4) ? Wx + (long)z * 1048576
                                : (z < 8) ? Wh + (long)(z - 4) * 1048576
                                          : Wyt;
    const int tx = threadIdx.x & 31, ty = threadIdx.x >> 5;
    const int rb = blockIdx.y * 32, cb = blockIdx.x * 32;
#pragma unroll
    for (int rr = 0; rr < 4; ++rr) {
        int r = ty + rr * 8;
        tile[r][tx] = S[(long)(rb + r) * 1024 + cb + tx];
    }
    __syncthreads();
#pragma unroll
    for (int rr = 0; rr < 4; ++rr) {
        int r = ty + rr * 8;
        D[(long)(cb + r) * 1024 + rb + tx] = f2bf(tile[tx][r]);
    }
}

// ---------- kernel: small init ----------
__global__ void init_small(const float* __restrict__ h0,
                           const float* __restrict__ bf_, const float* __restrict__ bi_,
                           const float* __restrict__ bc_, const float* __restrict__ bo_,
                           unsigned short* __restrict__ hbuf0,
                           float* __restrict__ bcat, unsigned int* __restrict__ flags) {
    int i = blockIdx.x * blockDim.x + threadIdx.x;
    if (i < 1024) flags[i] = 0u;
    if (i < 65536) hbuf0[i] = f2bf(h0[i]);
    if (i < 4096) {
        const float* bs = (i < 1024) ? bf_ : (i < 2048) ? bi_ : (i < 3072) ? bc_ : bo_;
        bcat[i] = bs[i & 1023];
    }
}

// ---------- kernel: 128x128 bf16 MFMA GEMM, A[M][K] x B^T[N][K] + bias ----------
template <int OUT_BF16>
__global__ __launch_bounds__(256) void gemm_bt(const unsigned short* __restrict__ A,
                                               const unsigned short* __restrict__ B,
                                               const float* __restrict__ bias,
                                               void* __restrict__ Cout,
                                               int M, int N, int K) {
    __shared__ unsigned short As[128 * 32];
    __shared__ unsigned short Bs[128 * 32];
    const int l = threadIdx.x;
    const int w = l >> 6, u = l & 63;
    const int wr = w >> 1, wc = w & 1;
    const long rowbase = (long)blockIdx.y * 128;
    const long colbase = (long)blockIdx.x * 128;

    f32x4 acc[4][4] = {};

    const int srow = l >> 2;
    const int sunit = l & 3;

    for (int k0 = 0; k0 < K; k0 += 32) {
#pragma unroll
        for (int i = 0; i < 2; ++i) {
            int row = i * 64 + srow;
            int su = sunit ^ (row & 3);
            gload16(&A[(rowbase + row) * K + k0 + su * 8], &As[i * 2048 + l * 8]);
            gload16(&B[(colbase + row) * K + k0 + su * 8], &Bs[i * 2048 + l * 8]);
        }
        __syncthreads();
        short8 a[4], b[4];
#pragma unroll
        for (int mi = 0; mi < 4; ++mi) {
            int row = wr * 64 + mi * 16 + (u & 15);
            a[mi] = *(const short8*)&As[row * 32 + (((u >> 4) ^ (row & 3))) * 8];
        }
#pragma unroll
        for (int ni = 0; ni < 4; ++ni) {
            int row = wc * 64 + ni * 16 + (u & 15);
            b[ni] = *(const short8*)&Bs[row * 32 + (((u >> 4) ^ (row & 3))) * 8];
        }
#pragma unroll
        for (int mi = 0; mi < 4; ++mi)
#pragma unroll
            for (int ni = 0; ni < 4; ++ni)
                acc[mi][ni] = __builtin_amdgcn_mfma_f32_16x16x32_bf16(a[mi], b[ni], acc[mi][ni], 0, 0, 0);
        __syncthreads();
    }

#pragma unroll
    for (int mi = 0; mi < 4; ++mi) {
#pragma unroll
        for (int ni = 0; ni < 4; ++ni) {
#pragma unroll
            for (int r = 0; r < 4; ++r) {
                long row = rowbase + wr * 64 + mi * 16 + (u >> 4) * 4 + r;
                long col = colbase + wc * 64 + ni * 16 + (u & 15);
                float v = acc[mi][ni][r] + bias[col];
                if (OUT_BF16)
                    ((unsigned short*)Cout)[row * N + col] = f2bf(v);
                else
                    ((float*)Cout)[row * N + col] = v;
            }
        }
    }
}

// ================= GO world: batch-partitioned XCD-local scan =================
// 256 WGs x 512 thr (8 waves). Group g = {bid: bid%8==g} (32 WGs, one XCD) owns batch
// rows [8g,8g+8). WG i=bid>>3 owns hidden cols [32i,32i+32) (=128 gate cols, 8 tiles).
// Wave v: K-slice s=v&3 ([256s,256s+256)), col-half nh=v>>2. Per-wave weights = 4 tiles
// x 8 kt x short8 = 128 VGPRs -> RESIDENT (R12 lesson: b[8][8]=256 VGPRs forced L2
// reload of 8MB/XCD/step; halving the per-wave footprint fixes it).
template <int FAST>
__device__ __forceinline__ void scan_go(
    int g, int i, int l, int w, int u,
    const unsigned short* __restrict__ Whc, const unsigned short* __restrict__ Xg,
    const unsigned short* __restrict__ h0bf, unsigned short* __restrict__ H,
    const float* __restrict__ c0, float* __restrict__ out_h, float* __restrict__ out_c,
    unsigned int* __restrict__ flags, f32x4 (*red)[8][64]) {

    const int s = w & 3, nh = w >> 2;          // K-slice, col-half
    const int rho = (l & 255) >> 5, chi = l & 31;  // epilogue target (l<256 only)
    const int arow = u & 15;
    const int kofs = (u >> 4) * 8;
    const int epi = (l < 256);

    // weights -> VGPRs (once): b[ga][kt] = tile(gate ga, col-half nh), K-slice s
    short8 b[4][8];
#pragma unroll
    for (int ga = 0; ga < 4; ++ga)
#pragma unroll
        for (int kt = 0; kt < 8; ++kt)
            b[ga][kt] = *(const short8*)&Whc[(size_t)(ga * 1024 + 32 * i + 16 * nh + arow) * 1024
                                             + s * 256 + kt * 32 + kofs];

    float c = 0.f;
    unsigned short xg[4] = {};
    if (epi) {
        c = c0[(size_t)(8 * g + rho) * 1024 + 32 * i + chi];
#pragma unroll
        for (int ga = 0; ga < 4; ++ga)
            xg[ga] = Xg[(size_t)(8 * g + rho) * 4096 + ga * 1024 + 32 * i + chi];
    }

    const short8 az = {};
    unsigned int* gctr = &flags[640 + g * 16];

#pragma unroll 1
    for (int t = 0; t < 256; ++t) {
        const unsigned short* hp = t ? (H + (size_t)(t - 1) * 65536 + 8 * g * 1024)
                                     : (h0bf + 8 * g * 1024);
        const unsigned short* ab = hp + (size_t)arow * 1024 + s * 256 + kofs;

        f32x4 acc[4] = {};
#pragma unroll
        for (int kt = 0; kt < 8; ++kt) {
            short8 a = (arow < 8) ? *(const short8*)(ab + kt * 32) : az;
#pragma unroll
            for (int ga = 0; ga < 4; ++ga)
                acc[ga] = __builtin_amdgcn_mfma_f32_16x16x32_bf16(a, b[ga][kt], acc[ga], 0, 0, 0);
        }

        // K-reduce staging: tile n = ga*2 + nh, K-slice s
#pragma unroll
        for (int ga = 0; ga < 4; ++ga)
            red[s][ga * 2 + nh][u] = acc[ga];
        __syncthreads();  // red ready

        if (epi) {
            float pre[4];
#pragma unroll
            for (int ga = 0; ga < 4; ++ga) {
                int n = ga * 2 + (chi >> 4);
                int sl = ((rho >> 2) << 4) + (chi & 15);
                int rg = rho & 3;
                const float* r0 = (const float*)&red[0][n][sl];
                const float* r1 = (const float*)&red[1][n][sl];
                const float* r2 = (const float*)&red[2][n][sl];
                const float* r3 = (const float*)&red[3][n][sl];
                pre[ga] = r0[rg] + r1[rg] + r2[rg] + r3[rg] + bf2f(xg[ga]);
            }
            float F = sigm(pre[0]);
            float I = sigm(pre[1]);
            float Cd = tanhf(pre[2]);
            float O = sigm(pre[3]);
            float cn = F * c + I * Cd;
            c = cn;
            float hf = tanhf(cn) * O;

            const size_t hidx = (size_t)(t * 64 + 8 * g + rho) * 1024 + 32 * i + chi;
            if (FAST) {
                unsigned hv = (unsigned)f2bf(hf);
                unsigned p01 = hv | (__shfl_down(hv, 1) << 16);
                unsigned p23 = __shfl_down(p01, 2);
                if (!(chi & 3)) {
                    unsigned long long v64 = (unsigned long long)p01 |
                                             ((unsigned long long)p23 << 32);
                    at_swap64((unsigned long long*)&H[hidx], v64);
                }
            } else {
                __hip_atomic_store(&H[hidx], f2bf(hf), __ATOMIC_RELAXED, __HIP_MEMORY_SCOPE_AGENT);
            }
            if (t == 255) {
                out_h[(size_t)(8 * g + rho) * 1024 + 32 * i + chi] = hf;
                out_c[(size_t)(8 * g + rho) * 1024 + 32 * i + chi] = cn;
            }
        }

        if (t < 255) {
            asm volatile("s_waitcnt vmcnt(0)" ::: "memory");  // h publish done in L2
            __syncthreads();  // whole WG drained; red reads done
            if (l == 0) {
                if (FAST)
                    at_add_nr(gctr, 1u);
                else
                    __hip_atomic_store(&flags[768 + g * 32 + i], (unsigned)(t + 1),
                                       __ATOMIC_RELAXED, __HIP_MEMORY_SCOPE_AGENT);
            }
            // Xg prefetch (l>0): hides HBM latency under the poll; l==0 defers so
            // at_poll's vmcnt(0) never waits on HBM
            if (epi && l > 0) {
#pragma unroll
                for (int ga = 0; ga < 4; ++ga)
                    xg[ga] = Xg[(size_t)((t + 1) * 64 + 8 * g + rho) * 4096 + ga * 1024 + 32 * i + chi];
            }
            if (FAST) {
                if (l == 0) {
                    const unsigned tgt = 32u * (unsigned)(t + 1);
                    unsigned long long wd0 = __builtin_amdgcn_s_memrealtime();
                    while (true) {
                        unsigned f = at_poll(gctr);
                        if (f >= tgt) break;
                        if (__builtin_amdgcn_s_memrealtime() - wd0 > WDOG_POLL) break;
                        __builtin_amdgcn_s_sleep(4);
                    }
                }
                __syncthreads();  // release whole WG
                if (l == 0) {
#pragma unroll
                    for (int ga = 0; ga < 4; ++ga)
                        xg[ga] = Xg[(size_t)((t + 1) * 64 + 8 * g + rho) * 4096 + ga * 1024 + 32 * i + chi];
                }
            } else {
                // per-wave poll of the 8 producers of this wave's K-slice
                const unsigned tgt = (unsigned)(t + 1);
                unsigned long long wd0 = __builtin_amdgcn_s_memrealtime();
                while (true) {
                    unsigned f = (u < 8) ? __hip_atomic_load(&flags[768 + g * 32 + 8 * s + u],
                                                             __ATOMIC_RELAXED, __HIP_MEMORY_SCOPE_AGENT)
                                         : tgt;
                    if (__all(f >= tgt)) break;
                    if (__builtin_amdgcn_s_memrealtime() - wd0 > WDOG_POLL) break;
                    __builtin_amdgcn_s_sleep(2);
                }
                __syncthreads();
            }
            asm volatile("" ::: "memory");
            __builtin_amdgcn_sched_barrier(0);
        }
    }
}

// ================= NOGO world: proven R5 64-WG scan (bids 0..63; waves 0..3 active) ===
__device__ __forceinline__ void scan64(
    int bid, int l, int w, int u,
    const unsigned short* __restrict__ Whc, const unsigned short* __restrict__ Xg,
    const unsigned short* __restrict__ h0bf, unsigned short* __restrict__ H,
    const float* __restrict__ c0, float* __restrict__ out_h, float* __restrict__ out_c,
    unsigned int* __restrict__ flags, f32x4 (*red)[4][4][64], unsigned short* hs) {

    const int j0 = bid * 16;
    const int jj = u & 15, q = u >> 4;
    const int act = (w < 4);

    short8 b[4][8] = {};
    float c[4] = {};
    unsigned short xg[4][4] = {};
    if (act) {
#pragma unroll
        for (int g = 0; g < 4; ++g)
#pragma unroll
            for (int kt = 0; kt < 8; ++kt)
                b[g][kt] = *(const short8*)&Whc[(size_t)(g * 1024 + j0 + jj) * 1024 + w * 256 + kt * 32 + q * 8];
#pragma unroll
        for (int r = 0; r < 4; ++r)
            c[r] = c0[(size_t)(w * 16 + q * 4 + r) * 1024 + j0 + jj];
#pragma unroll
        for (int g = 0; g < 4; ++g)
#pragma unroll
            for (int r = 0; r < 4; ++r)
                xg[g][r] = Xg[(size_t)(w * 16 + q * 4 + r) * 4096 + g * 1024 + j0 + jj];
    }

    const int srow_ = (l & 255) >> 2, sqtr = l & 3;

#pragma unroll 1
    for (int t = 0; t < 256; ++t) {
        const unsigned short* hp = t ? (H + (size_t)(t - 1) * 65536) : h0bf;

        f32x4 acc[4][4] = {};
        if (act) {
#pragma unroll
            for (int kt = 0; kt < 8; ++kt) {
                short8 a[4];
#pragma unroll
                for (int m = 0; m < 4; ++m)
                    a[m] = *(const short8*)&hp[(size_t)(m * 16 + jj) * 1024 + w * 256 + kt * 32 + q * 8];
#pragma unroll
                for (int m = 0; m < 4; ++m)
#pragma unroll
                    for (int g = 0; g < 4; ++g)
                        acc[m][g] = __builtin_amdgcn_mfma_f32_16x16x32_bf16(a[m], b[g][kt], acc[m][g], 0, 0, 0);
            }
        }

        __syncthreads();
        if (act) {
#pragma unroll
            for (int m = 0; m < 4; ++m)
#pragma unroll
                for (int g = 0; g < 4; ++g)
                    red[m][w][g][u] = acc[m][g];
        }
        __syncthreads();

        if (act) {
            f32x4 gate[4];
#pragma unroll
            for (int g = 0; g < 4; ++g) {
                gate[g] = red[w][0][g][u];
#pragma unroll
                for (int w2 = 1; w2 < 4; ++w2)
                    gate[g] += red[w][w2][g][u];
            }
#pragma unroll
            for (int r = 0; r < 4; ++r) {
                float F = sigm(gate[0][r] + bf2f(xg[0][r]));
                float I = sigm(gate[1][r] + bf2f(xg[1][r]));
                float Cd = tanhf(gate[2][r] + bf2f(xg[2][r]));
                float O = sigm(gate[3][r] + bf2f(xg[3][r]));
                float cn = F * c[r] + I * Cd;
                c[r] = cn;
                float hf = tanhf(cn) * O;
                int row = w * 16 + q * 4 + r;
                hs[row * 16 + jj] = f2bf(hf);
                if (t == 255) {
                    out_h[(size_t)row * 1024 + j0 + jj] = hf;
                    out_c[(size_t)row * 1024 + j0 + jj] = cn;
                }
            }
        }
        __syncthreads();

        if (l < 256) {
            unsigned long long v = *(const unsigned long long*)&hs[srow_ * 16 + sqtr * 4];
            __hip_atomic_store((unsigned long long*)&H[(size_t)(t * 64 + srow_) * 1024 + j0 + sqtr * 4],
                               v, __ATOMIC_RELAXED, __HIP_MEMORY_SCOPE_AGENT);
        }

        if (t < 255) {
            asm volatile("s_waitcnt vmcnt(0)" ::: "memory");
            __syncthreads();
            if (l == 0)
                __hip_atomic_store(&flags[512 + bid], (unsigned)(t + 1),
                                   __ATOMIC_RELAXED, __HIP_MEMORY_SCOPE_AGENT);
            if (act) {
#pragma unroll
                for (int g = 0; g < 4; ++g)
#pragma unroll
                    for (int r = 0; r < 4; ++r)
                        xg[g][r] = Xg[(size_t)((t + 1) * 64 + w * 16 + q * 4 + r) * 4096 + g * 1024 + j0 + jj];
            }
            const unsigned tgt = (unsigned)(t + 1);
            unsigned long long wd0 = __builtin_amdgcn_s_memrealtime();
            while (true) {
                unsigned f = (act && jj < 16) ? __hip_atomic_load(&flags[512 + 16 * w + jj],
                                                                  __ATOMIC_RELAXED, __HIP_MEMORY_SCOPE_AGENT)
                                              : tgt;
                if (__all(f >= tgt)) break;
                if (__builtin_amdgcn_s_memrealtime() - wd0 > WDOG_POLL) break;
                __builtin_amdgcn_s_sleep(4);
            }
            asm volatile("" ::: "memory");
            __builtin_amdgcn_sched_barrier(0);
        }
    }
}

// ================= dispatcher kernel =================
__global__ __launch_bounds__(512, 1) void lstm_scan(
    const unsigned short* __restrict__ Whc, const unsigned short* __restrict__ Xg,
    const unsigned short* __restrict__ h0bf, unsigned short* __restrict__ H,
    const float* __restrict__ c0, float* __restrict__ out_h, float* __restrict__ out_c,
    unsigned int* __restrict__ flags) {
    __shared__ __align__(16) char smem_[67584];   // GO: red[4][8][64] 32KB | NOGO: 64KB + hs 2KB
    __shared__ int s_dec;
    __shared__ int s_allsame;
    const int l = threadIdx.x, w = l >> 6, u = l & 63;
    const int bid = blockIdx.x;

    // ---- residency vote: arrive, decide (bid 0), read decision ----
    if (l == 0) {
        __hip_atomic_fetch_add(&flags[576], 1u, __ATOMIC_RELAXED, __HIP_MEMORY_SCOPE_AGENT);
        unsigned dec = 0;
        if (bid == 0) {
            unsigned long long t0 = __builtin_amdgcn_s_memrealtime();
            while (true) {
                unsigned cnt = __hip_atomic_load(&flags[576], __ATOMIC_RELAXED,
                                                 __HIP_MEMORY_SCOPE_AGENT);
                if (cnt >= 256u) { dec = 1u; break; }
                if (__builtin_amdgcn_s_memrealtime() - t0 > DEC_WAIT) { dec = 2u; break; }
                __builtin_amdgcn_s_sleep(8);
            }
            __hip_atomic_store(&flags[577], dec, __ATOMIC_RELAXED, __HIP_MEMORY_SCOPE_AGENT);
        } else {
            unsigned long long t0 = __builtin_amdgcn_s_memrealtime();
            while (true) {
                dec = __hip_atomic_load(&flags[577], __ATOMIC_RELAXED, __HIP_MEMORY_SCOPE_AGENT);
                if (dec) break;
                if (__builtin_amdgcn_s_memrealtime() - t0 > WDOG_DEC) { dec = 2u; break; }
                __builtin_amdgcn_s_sleep(8);
            }
        }
        s_dec = (int)dec;
    }
    __syncthreads();

    if (s_dec == 1) {
        // ---- GO: all 256 WGs resident. Per-group XCD homogeneity check ----
        const int g = bid & 7, i = bid >> 3;
        unsigned int* xcc = flags + 256;
        unsigned my_xcc;
        asm volatile("s_getreg_b32 %0, hwreg(HW_REG_XCC_ID)" : "=s"(my_xcc));
        if (l == 0)
            __hip_atomic_store(&xcc[bid], 256u | (my_xcc & 255u),
                               __ATOMIC_RELAXED, __HIP_MEMORY_SCOPE_AGENT);
        if (w == 0) {
            unsigned v = 256u;
            unsigned long long wd0 = __builtin_amdgcn_s_memrealtime();
            int timeout = 0;
            while (true) {
                v = (u < 32) ? __hip_atomic_load(&xcc[(u << 3) | g], __ATOMIC_RELAXED,
                                                 __HIP_MEMORY_SCOPE_AGENT)
                             : 257u;
                unsigned long long rdy = __ballot(v >= 256u);
                if (rdy == ~0ull) break;
                if (__builtin_amdgcn_s_memrealtime() - wd0 > WDOG_DEC) { timeout = 1; break; }
                __builtin_amdgcn_s_sleep(8);
            }
            unsigned first = __shfl(v, 0);
            int same = ((u < 32) ? (v == first) : 1) ? 1 : 0;
            unsigned long long m = __ballot(same);
            if (u == 0) s_allsame = (!timeout && m == ~0ull) ? 1 : 0;
        }
        __syncthreads();

        f32x4 (*red)[8][64] = (f32x4(*)[8][64])smem_;
        if (s_allsame)
            scan_go<1>(g, i, l, w, u, Whc, Xg, h0bf, H, c0, out_h, out_c, flags, red);
        else
            scan_go<0>(g, i, l, w, u, Whc, Xg, h0bf, H, c0, out_h, out_c, flags, red);
    } else {
        // ---- NOGO: bids >= 64 exit (frees CUs); bids < 64 run proven R5 scan ----
        if (bid >= 64) return;
        f32x4 (*red64)[4][4][64] = (f32x4(*)[4][4][64])smem_;
        unsigned short* hs = (unsigned short*)(smem_ + 65536);
        scan64(bid, l, w, u, Whc, Xg, h0bf, H, c0, out_h, out_c, flags, red64, hs);
    }
}

// ---------- launch ----------
extern "C" void kernel_launch(void* const* d_in, const int* in_sizes, int n_in,
                              void* d_out, int out_size, void* d_ws, size_t ws_size,
                              hipStream_t stream) {
    const float* steps = (const float*)d_in[0];
    const float* h0 = (const float*)d_in[1];
    const float* c0 = (const float*)d_in[2];
    const float* Wfx = (const float*)d_in[3];
    const float* Wfh = (const float*)d_in[4];
    const float* bf_ = (const float*)d_in[5];
    const float* Wix = (const float*)d_in[6];
    const float* Wih = (const float*)d_in[7];
    const float* bi_ = (const float*)d_in[8];
    const float* Wcx = (const float*)d_in[9];
    const float* Wch = (const float*)d_in[10];
    const float* bc_ = (const float*)d_in[11];
    const float* Wox = (const float*)d_in[12];
    const float* Woh = (const float*)d_in[13];
    const float* bo_ = (const float*)d_in[14];
    const float* Wy = (const float*)d_in[15];
    const float* by_ = (const float*)d_in[16];

    char* ws = (char*)d_ws;
    unsigned short* Xbf = (unsigned short*)(ws + 0L);           //  33,554,432 B
    unsigned short* Xg  = (unsigned short*)(ws + 33554432L);    // 134,217,728 B
    unsigned short* H   = (unsigned short*)(ws + 167772160L);   //  33,554,432 B
    unsigned short* Wx  = (unsigned short*)(ws + 201326592L);   //   8,388,608 B
    unsigned short* Wh  = (unsigned short*)(ws + 209715200L);   //   8,388,608 B
    unsigned short* Wyt = (unsigned short*)(ws + 218103808L);   //   2,097,152 B
    float* bcat         = (float*)(ws + 220200960L);            //      16,384 B
    unsigned short* hbuf0 = (unsigned short*)(ws + 220217344L); //     131,072 B
    unsigned int* flags = (unsigned int*)(ws + 220348416L);     //       4,096 B

    float* out_y = (float*)d_out;
    float* out_h = out_y + 16777216L;
    float* out_c = out_h + 65536L;

    // 1. convert X to bf16
    conv_bf16<<<2048, 256, 0, stream>>>((const float4*)steps, (ushort4*)Xbf, 4194304);

    // 2. transpose-pack all weights to bf16 [N][K]
    PackArgs pa;
    pa.src[0] = Wfx; pa.src[1] = Wix; pa.src[2] = Wcx; pa.src[3] = Wox;
    pa.src[4] = Wfh; pa.src[5] = Wih; pa.src[6] = Wch; pa.src[7] = Woh;
    pa.src[8] = Wy;
    pack_w<<<dim3(32, 32, 9), 256, 0, stream>>>(pa, Wx, Wh, Wyt);

    // 3. small init (h0->bf16, bias concat, flags = 0) — runs every replay
    init_small<<<256, 256, 0, stream>>>(h0, bf_, bi_, bc_, bo_, hbuf0, bcat, flags);

    // 4. Xg = X @ Wxcat + bcat   (M=16384, N=4096, K=1024), bf16 out
    gemm_bt<1><<<dim3(32, 128), 256, 0, stream>>>(Xbf, Wx, bcat, Xg, 16384, 4096, 1024);

    // 5. persistent scan: 256 WGs x 512 thr, residency vote, XCD-local FAST path
    lstm_scan<<<256, 512, 0, stream>>>(Wh, Xg, hbuf0, H, c0, out_h, out_c, flags);

    // 6. Y = H @ Wy + by  (M=16384, N=1024, K=1024), fp32 out to d_out
    gemm_bt<0><<<dim3(8, 128), 256, 0, stream>>>(H, Wyt, by_, (void*)d_out, 16384, 1024, 1024);
}